// Round 10
// baseline (1700.860 us; speedup 1.0000x reference)
//
#include <hip/hip_runtime.h>

// ---------------------------------------------------------------------------
// Problem constants: B=2, L=1024, D=1024, H=16, DK=DV=64
// ---------------------------------------------------------------------------

#define TILE_M 64
#define TILE_N 64
#define TILE_K 16

struct GemmSlot { const float* W; const float* bias; float* out; int mode; };
struct GemmBatch { GemmSlot s[4]; };

__device__ __forceinline__ float silu_(float x) {
  return x / (1.f + __expf(-x));
}
__device__ __forceinline__ float sigm_(float x) {
  return 1.f / (1.f + __expf(-x));
}
__device__ __forceinline__ float rdl_(float v, int l) {
  return __int_as_float(__builtin_amdgcn_readlane(__float_as_int(v), l));
}

// ---------------------------------------------------------------------------
// Generic fp32 GEMM: C = act(A[M,K] @ W[K,N] + bias), act/store per mode.
// mode 0: raw, linear store; mode 1: silu, linear; mode 2: silu, scatter BHLd
// ---------------------------------------------------------------------------
__global__ __launch_bounds__(256) void gemm_act(
    const float* __restrict__ A, GemmBatch gb, int M, int N, int K)
{
  const GemmSlot sl = gb.s[blockIdx.z];
  const float* __restrict__ W = sl.W;

  __shared__ float As[TILE_K][TILE_M + 4];
  __shared__ float Ws[TILE_K][TILE_N];

  const int tid = threadIdx.x;
  const int bm = blockIdx.x * TILE_M;
  const int bn = blockIdx.y * TILE_N;
  const int tm = (tid >> 4) << 2;
  const int tn = (tid & 15) << 2;
  const int la_r = tid >> 2;
  const int la_c = (tid & 3) << 2;
  const int lw_r = tid >> 4;
  const int lw_c = (tid & 15) << 2;

  float acc[4][4] = {{0.f,0.f,0.f,0.f},{0.f,0.f,0.f,0.f},
                     {0.f,0.f,0.f,0.f},{0.f,0.f,0.f,0.f}};

  for (int kb = 0; kb < K; kb += TILE_K) {
    float4 av = *(const float4*)&A[(size_t)(bm + la_r) * K + kb + la_c];
    float4 wv = *(const float4*)&W[(size_t)(kb + lw_r) * N + bn + lw_c];
    __syncthreads();
    As[la_c + 0][la_r] = av.x;
    As[la_c + 1][la_r] = av.y;
    As[la_c + 2][la_r] = av.z;
    As[la_c + 3][la_r] = av.w;
    *(float4*)&Ws[lw_r][lw_c] = wv;
    __syncthreads();
#pragma unroll
    for (int kk = 0; kk < TILE_K; ++kk) {
      float4 a = *(const float4*)&As[kk][tm];
      float4 b = *(const float4*)&Ws[kk][tn];
      acc[0][0] = fmaf(a.x, b.x, acc[0][0]);
      acc[0][1] = fmaf(a.x, b.y, acc[0][1]);
      acc[0][2] = fmaf(a.x, b.z, acc[0][2]);
      acc[0][3] = fmaf(a.x, b.w, acc[0][3]);
      acc[1][0] = fmaf(a.y, b.x, acc[1][0]);
      acc[1][1] = fmaf(a.y, b.y, acc[1][1]);
      acc[1][2] = fmaf(a.y, b.z, acc[1][2]);
      acc[1][3] = fmaf(a.y, b.w, acc[1][3]);
      acc[2][0] = fmaf(a.z, b.x, acc[2][0]);
      acc[2][1] = fmaf(a.z, b.y, acc[2][1]);
      acc[2][2] = fmaf(a.z, b.z, acc[2][2]);
      acc[2][3] = fmaf(a.z, b.w, acc[2][3]);
      acc[3][0] = fmaf(a.w, b.x, acc[3][0]);
      acc[3][1] = fmaf(a.w, b.y, acc[3][1]);
      acc[3][2] = fmaf(a.w, b.z, acc[3][2]);
      acc[3][3] = fmaf(a.w, b.w, acc[3][3]);
    }
  }

  const float* bias = sl.bias;
  float* out = sl.out;
  const int mode = sl.mode;
#pragma unroll
  for (int i = 0; i < 4; ++i) {
#pragma unroll
    for (int j = 0; j < 4; ++j) {
      int m = bm + tm + i, n = bn + tn + j;
      float c = acc[i][j] + bias[n];
      if (mode >= 1) c = silu_(c);
      if (mode == 2) {
        int h = n >> 6, d = n & 63;
        int b = m >> 10, l = m & 1023;
        out[(((size_t)(b * 16 + h)) * 1024 + l) * 64 + d] = c;
      } else {
        out[(size_t)m * N + n] = c;
      }
    }
  }
}

// ---------------------------------------------------------------------------
// Scalar projections, packed: scl[bh][t][8], slot 0=beta,1=fd,2=sd,3=fg,4=sg
// ---------------------------------------------------------------------------
__global__ __launch_bounds__(256) void scalar_proj(
    const float* __restrict__ hs,
    const float* __restrict__ Wb,  const float* __restrict__ bb,
    const float* __restrict__ Wfd, const float* __restrict__ bfd, const float* __restrict__ fdb,
    const float* __restrict__ Wsd, const float* __restrict__ bsd, const float* __restrict__ sdb,
    const float* __restrict__ Wfg, const float* __restrict__ bfg,
    const float* __restrict__ Wsg, const float* __restrict__ bsg,
    float* __restrict__ scl)
{
  int gid = blockIdx.x * 256 + threadIdx.x;  // < 2048*80
  int m = gid / 80;
  int c = gid - m * 80;
  int type = c >> 4;
  int h = c & 15;
  const float* W; const float* bias; float extra = 0.f;
  switch (type) {
    case 0:  W = Wb;  bias = bb;  break;
    case 1:  W = Wfd; bias = bfd; extra = fdb[h]; break;
    case 2:  W = Wsd; bias = bsd; extra = sdb[h]; break;
    case 3:  W = Wfg; bias = bfg; break;
    default: W = Wsg; bias = bsg; break;
  }
  const float* hrow = hs + (size_t)m * 1024;
  float s = 0.f;
  for (int k2 = 0; k2 < 1024; ++k2)
    s = fmaf(hrow[k2], W[k2 * 16 + h], s);
  s += bias[h] + extra;
  float r = sigm_(s);
  int b = m >> 10, l = m & 1023;
  scl[((size_t)((b * 16 + h) * 1024 + l)) * 8 + type] = r;
}

// ---------------------------------------------------------------------------
// Pre-normalize q and k in place: x *= rsqrt(sum_64(x^2)+1e-6).
// ---------------------------------------------------------------------------
__global__ __launch_bounds__(256) void prenorm(float* __restrict__ p)
{
  int wid = blockIdx.x * 4 + (threadIdx.x >> 6);
  int lane = threadIdx.x & 63;
  size_t idx = (size_t)wid * 64 + lane;
  float x = p[idx];
  float ss = x * x;
#pragma unroll
  for (int d2 = 32; d2 >= 1; d2 >>= 1) ss += __shfl_xor(ss, d2, 64);
  p[idx] = x * rsqrtf(ss + 1e-6f);
}

// ---------------------------------------------------------------------------
// Sequential scan, v10: 4 waves per (b,h), ONE register pass + ONE barrier
// per step. During step t's update pass (the only pass), each wave also
// accumulates the four dots for step t+1 against the UPDATED state:
//   ef1=k_{t+1}.Tf, es1=k_{t+1}.Ts, gf1=q_{t+1}.Tf, gs1=q_{t+1}.Ts
// These partials are exchanged via LDS float2 arrays (8B stride -> 2-way
// bank aliasing = free; r9's float4 was an 8-way conflict, 2.6M cycles).
// State is refolded to ACTUAL scale every step (state and partials *= afT)
// so no alpha bookkeeping carries. qk_{t+1} and the 1/fd,1/sd coefficient
// chain are precomputed one step ahead (off critical path). k/q per-lane
// loads are 2-deep prefetched (consumed mid-step by readlane broadcast).
// ---------------------------------------------------------------------------
__global__ __launch_bounds__(256) void scan_kernel(
    const float* __restrict__ qg, const float* __restrict__ kg, const float* __restrict__ vg,
    const float* __restrict__ scl, const float* __restrict__ rfx, float* __restrict__ og)
{
  const int bh = blockIdx.x;     // 0..31
  const int tid = threadIdx.x;
  const int lane = tid & 63;     // column index
  const int w = tid >> 6;        // wave id: rows [16w, 16w+16)
  const float rf = rfx[0];
  const float rf2 = rf * rf;

  __shared__ float2 pE[2][4][64];  // {ef,es} partials, double-buffered
  __shared__ float2 pG[2][4][64];  // {gf,gs} partials

  float Sf[16], Ss[16];
#pragma unroll
  for (int j = 0; j < 16; ++j) { Sf[j] = 0.f; Ss[j] = 0.f; }

  const float* kb = kg + (size_t)bh * 65536;
  const float* qb = qg + (size_t)bh * 65536;
  const float* vb = vg + (size_t)bh * 65536;
  const float* sb = scl + (size_t)bh * 8192;
  const int b = bh >> 4, h = bh & 15;
  float* ob = og + (size_t)b * (1024 * 1024) + h * 64;  // + t*1024 + lane

  // ---- prologue: t=0 inputs, qk_0, k_0 row broadcasts, step-0 coeffs ----
  float kv0 = kb[lane], qv0 = qb[lane];
  float kvA = kb[64 + lane], qvA = qb[64 + lane];   // t=1 per-lane
  float vv = vb[lane];
  float4 sc = *(const float4*)&sb[0];
  float sg4 = sb[4];

  float qkc = kv0 * qv0;
#pragma unroll
  for (int d2 = 32; d2 >= 1; d2 >>= 1) qkc += __shfl_xor(qkc, d2, 64);

  float kr[16];
#pragma unroll
  for (int j = 0; j < 16; ++j) kr[j] = rdl_(kv0, w * 16 + j);

  float braf, bras, cfs, csf;
  {
    const float raf = 1.f / sc.y;
    const float ras = 1.f / sc.z;
    braf = sc.x * raf;
    bras = sc.x * ras;
    cfs = rf * sc.z * raf;
    csf = rf * sc.y * ras;
  }

  float ef = 0.f, es = 0.f, gf = 0.f, gs = 0.f;   // dots vs zero state
  float Nf = 0.f, Ns = 0.f, Cc = 0.f;             // actual norms / cross

  for (int t = 0; t < 1024; ++t) {
    const int t1 = (t + 1) & 1023;
    const int t2 = (t + 2) & 1023;

    // ---- prefetch: k/q two steps ahead, v/sc one step ahead ----
    const float kvB = kb[t2 * 64 + lane];
    const float qvB = qb[t2 * 64 + lane];
    const float vn  = vb[t1 * 64 + lane];
    const float4 scn = *(const float4*)&sb[(size_t)t1 * 8];
    const float sgn = sb[(size_t)t1 * 8 + 4];

    // ---- qk for step t+1 (consumed next iteration) ----
    float qkn = kvA * qvA;
#pragma unroll
    for (int d2 = 32; d2 >= 1; d2 >>= 1) qkn += __shfl_xor(qkn, d2, 64);

    // ---- broadcast rows of k_{t+1}, q_{t+1} for the fused dots ----
    float kr1[16], qr1[16];
#pragma unroll
    for (int j = 0; j < 16; ++j) {
      kr1[j] = rdl_(kvA, w * 16 + j);
      qr1[j] = rdl_(qvA, w * 16 + j);
    }

    // ---- coefficients for step t+1 (div chain off critical path) ----
    const float rafn = 1.f / scn.y;
    const float rasn = 1.f / scn.z;
    const float brafn = scn.x * rafn;
    const float brasn = scn.x * rasn;
    const float cfsn = rf * scn.z * rafn;
    const float csfn = rf * scn.y * rasn;

    // ---- the ONLY barrier: collect partial dots from all 4 waves ----
    if (t > 0) {
      __syncthreads();
      const int pr = (t - 1) & 1;
      float2 e0 = pE[pr][0][lane], e1 = pE[pr][1][lane];
      float2 e2 = pE[pr][2][lane], e3 = pE[pr][3][lane];
      float2 g0 = pG[pr][0][lane], g1 = pG[pr][1][lane];
      float2 g2 = pG[pr][2][lane], g3 = pG[pr][3][lane];
      ef = (e0.x + e1.x) + (e2.x + e3.x);
      es = (e0.y + e1.y) + (e2.y + e3.y);
      gf = (g0.x + g1.x) + (g2.x + g3.x);
      gs = (g0.y + g1.y) + (g2.y + g3.y);
    }

    const float bt = sc.x, fdt = sc.y, sdt = sc.z, fgt = sc.w, sgt = sg4;

    // ---- head: decay (scalar), error, update coefficients ----
    const float EF = fdt * ef, ES = sdt * es;
    const float errf = vv - EF, errs = vv - ES;
    const float beff = braf * errf, bess = bras * errs;

    // ---- analytic output dots (exact) ----
    const float sfq = fmaf(qkc, beff, gf);   // q . Sf_updated (repr)
    const float svq = fmaf(qkc, bess, gs);
    const float of = fmaf(cfs, svq, sfq);    // q . Tf (repr)
    const float os = fmaf(csf, sfq, svq);

    // ---- A-reduce: 5 quadratic sums (overlaps pass2) ----
    float p1 = errf * errf, p2 = errs * errs, p3 = errf * errs;
    float p4 = vv * errf, p5 = vv * errs;
#pragma unroll
    for (int d2 = 32; d2 >= 1; d2 >>= 1) {
      p1 += __shfl_xor(p1, d2, 64);
      p2 += __shfl_xor(p2, d2, 64);
      p3 += __shfl_xor(p3, d2, 64);
      p4 += __shfl_xor(p4, d2, 64);
      p5 += __shfl_xor(p5, d2, 64);
    }

    // ---- single register pass: update + combine + fused t+1 dots ----
    float ef1 = 0.f, es1 = 0.f, gf1 = 0.f, gs1 = 0.f;
#pragma unroll
    for (int j = 0; j < 16; ++j) {
      float sfv = fmaf(kr[j], beff, Sf[j]);
      float svv = fmaf(kr[j], bess, Ss[j]);
      float tf = fmaf(cfs, svv, sfv);
      float ts = fmaf(csf, sfv, svv);
      ef1 = fmaf(kr1[j], tf, ef1);
      es1 = fmaf(kr1[j], ts, es1);
      gf1 = fmaf(qr1[j], tf, gf1);
      gs1 = fmaf(qr1[j], ts, gs1);
      Sf[j] = tf; Ss[j] = ts;
    }

    // ---- closed-form norm recurrences + cap ----
    const float A1 = p4 - p1, A2 = p5 - p2;
    const float A3 = p1, A4 = p2, A5 = p3;
    const float A67 = p4 + p5 - 2.f * p3;
    const float b2s = bt * bt;
    const float Nfd = fmaf(fdt * fdt, Nf, fmaf(2.f * bt, A1, b2s * A3));
    const float Nsd = fmaf(sdt * sdt, Ns, fmaf(2.f * bt, A2, b2s * A4));
    const float Cd  = fmaf(fdt * sdt, Cc, fmaf(bt, A67, b2s * A5));
    const float NTf = Nfd + 2.f * rf * Cd + rf2 * Nsd;
    const float NTs = Nsd + 2.f * rf * Cd + rf2 * Nfd;
    const float CT  = (1.f + rf2) * Cd + rf * (Nfd + Nsd);
    const bool capf = NTf > 4096.f;
    const bool caps = NTs > 4096.f;
    const float scf = capf ? 64.f * rsqrtf(NTf) : 1.f;
    const float scs = caps ? 64.f * rsqrtf(NTs) : 1.f;
    const float afT = fdt * scf;   // total repr->actual scale this step
    const float asT = sdt * scs;
    Nf = capf ? 4096.f : NTf;
    Ns = caps ? 4096.f : NTs;
    Cc = scf * scs * CT;

    // ---- output (actual scale) ----
    if (w == 0) ob[(size_t)t * 1024 + lane] = fgt * afT * of + sgt * asT * os;

    // ---- refold state and outgoing partials to actual scale ----
#pragma unroll
    for (int j = 0; j < 16; ++j) { Sf[j] *= afT; Ss[j] *= asT; }
    const int par = t & 1;
    pE[par][w][lane] = make_float2(afT * ef1, asT * es1);
    pG[par][w][lane] = make_float2(afT * gf1, asT * gs1);

    // ---- rotate pipeline ----
#pragma unroll
    for (int j = 0; j < 16; ++j) kr[j] = kr1[j];
    kvA = kvB; qvA = qvB; vv = vn; sc = scn; sg4 = sgn; qkc = qkn;
    braf = brafn; bras = brasn; cfs = cfsn; csf = csfn;
  }
}

// ---------------------------------------------------------------------------
// Gated RMSNorm: og = o * rsqrt(mean(o^2)+eps) * onorm_w * silu_g (g pre-silu'd)
// ---------------------------------------------------------------------------
__global__ __launch_bounds__(256) void rms_gate(
    const float* __restrict__ o, const float* __restrict__ gsil,
    const float* __restrict__ onw, float* __restrict__ og)
{
  int gi = blockIdx.x * 4 + (threadIdx.x >> 6);
  int lane = threadIdx.x & 63;
  size_t idx = (size_t)gi * 64 + lane;
  float x = o[idx];
  float ss = x * x;
#pragma unroll
  for (int d2 = 32; d2 >= 1; d2 >>= 1) ss += __shfl_xor(ss, d2, 64);
  float r = rsqrtf(ss * (1.f / 64.f) + 1e-5f);
  og[idx] = x * r * onw[lane] * gsil[idx];
}

// ---------------------------------------------------------------------------
// Host launcher
// ---------------------------------------------------------------------------
extern "C" void kernel_launch(void* const* d_in, const int* in_sizes, int n_in,
                              void* d_out, int out_size, void* d_ws, size_t ws_size,
                              hipStream_t stream)
{
  const float* hs  = (const float*)d_in[0];
  const float* Wq  = (const float*)d_in[1];
  const float* bq  = (const float*)d_in[2];
  const float* Wk  = (const float*)d_in[3];
  const float* bk  = (const float*)d_in[4];
  const float* Wv  = (const float*)d_in[5];
  const float* bv  = (const float*)d_in[6];
  const float* Wb  = (const float*)d_in[7];
  const float* bb  = (const float*)d_in[8];
  const float* Wfd = (const float*)d_in[9];
  const float* bfd = (const float*)d_in[10];
  const float* fdb = (const float*)d_in[11];
  const float* Wsd = (const float*)d_in[12];
  const float* bsd = (const float*)d_in[13];
  const float* sdb = (const float*)d_in[14];
  const float* Wfg = (const float*)d_in[15];
  const float* bfg = (const float*)d_in[16];
  const float* Wsg = (const float*)d_in[17];
  const float* bsg = (const float*)d_in[18];
  const float* Wg  = (const float*)d_in[19];
  const float* bg  = (const float*)d_in[20];
  const float* onw = (const float*)d_in[21];
  const float* Wo  = (const float*)d_in[22];
  const float* bo  = (const float*)d_in[23];
  const float* rfx = (const float*)d_in[24];

  float* ws = (float*)d_ws;
  const size_t TWO_M = (size_t)1 << 21;  // 2M floats = B*H*L*64
  float* q_ws  = ws;                     // q and k contiguous for prenorm
  float* k_ws  = ws + TWO_M;
  float* v_ws  = ws + 2 * TWO_M;
  float* g_ws  = ws + 3 * TWO_M;
  float* o_ws  = ws + 4 * TWO_M;
  float* scl_ws = ws + 5 * TWO_M;        // 32*1024*8 floats packed scalars
  float* og_ws = q_ws;  // reuse q buffer (scan has consumed it)

  // 1) big projections: q,k,v (silu + scatter), g (silu, linear)
  GemmBatch gb1;
  gb1.s[0].W = Wq; gb1.s[0].bias = bq; gb1.s[0].out = q_ws; gb1.s[0].mode = 2;
  gb1.s[1].W = Wk; gb1.s[1].bias = bk; gb1.s[1].out = k_ws; gb1.s[1].mode = 2;
  gb1.s[2].W = Wv; gb1.s[2].bias = bv; gb1.s[2].out = v_ws; gb1.s[2].mode = 2;
  gb1.s[3].W = Wg; gb1.s[3].bias = bg; gb1.s[3].out = g_ws; gb1.s[3].mode = 1;
  gemm_act<<<dim3(32, 16, 4), 256, 0, stream>>>(hs, gb1, 2048, 1024, 1024);

  // 2) per-head scalar projections (packed)
  scalar_proj<<<640, 256, 0, stream>>>(hs, Wb, bb, Wfd, bfd, fdb, Wsd, bsd, sdb,
                                       Wfg, bfg, Wsg, bsg, scl_ws);

  // 3) pre-normalize q,k (contiguous 4M floats = 65536 rows of 64)
  prenorm<<<16384, 256, 0, stream>>>(q_ws);

  // 4) sequential dual-state delta-rule scan: 4 waves, 1 pass, 1 barrier
  scan_kernel<<<32, 256, 0, stream>>>(q_ws, k_ws, v_ws, scl_ws, rfx, o_ws);

  // 5) gated RMSNorm
  rms_gate<<<8192, 256, 0, stream>>>(o_ws, g_ws, onw, og_ws);

  // 6) output projection -> d_out
  GemmBatch gb2;
  gb2.s[0].W = Wo; gb2.s[0].bias = bo; gb2.s[0].out = (float*)d_out; gb2.s[0].mode = 0;
  gb2.s[1] = gb2.s[0]; gb2.s[2] = gb2.s[0]; gb2.s[3] = gb2.s[0];
  gemm_act<<<dim3(32, 16, 1), 256, 0, stream>>>(og_ws, gb2, 2048, 1024, 1024);
}

// Round 11
// 1683.159 us; speedup vs baseline: 1.0105x; 1.0105x over previous
//
#include <hip/hip_runtime.h>

// ---------------------------------------------------------------------------
// Problem constants: B=2, L=1024, D=1024, H=16, DK=DV=64
// ---------------------------------------------------------------------------

#define TILE_M 64
#define TILE_N 64
#define TILE_K 16

struct GemmSlot { const float* W; const float* bias; float* out; int mode; };
struct GemmBatch { GemmSlot s[4]; };

__device__ __forceinline__ float silu_(float x) {
  return x / (1.f + __expf(-x));
}
__device__ __forceinline__ float sigm_(float x) {
  return 1.f / (1.f + __expf(-x));
}
__device__ __forceinline__ float rdl_(float v, int l) {
  return __int_as_float(__builtin_amdgcn_readlane(__float_as_int(v), l));
}

// ---------------------------------------------------------------------------
// Generic fp32 GEMM: C = act(A[M,K] @ W[K,N] + bias), act/store per mode.
// mode 0: raw, linear store; mode 1: silu, linear; mode 2: silu, scatter BHLd
// ---------------------------------------------------------------------------
__global__ __launch_bounds__(256) void gemm_act(
    const float* __restrict__ A, GemmBatch gb, int M, int N, int K)
{
  const GemmSlot sl = gb.s[blockIdx.z];
  const float* __restrict__ W = sl.W;

  __shared__ float As[TILE_K][TILE_M + 4];
  __shared__ float Ws[TILE_K][TILE_N];

  const int tid = threadIdx.x;
  const int bm = blockIdx.x * TILE_M;
  const int bn = blockIdx.y * TILE_N;
  const int tm = (tid >> 4) << 2;
  const int tn = (tid & 15) << 2;
  const int la_r = tid >> 2;
  const int la_c = (tid & 3) << 2;
  const int lw_r = tid >> 4;
  const int lw_c = (tid & 15) << 2;

  float acc[4][4] = {{0.f,0.f,0.f,0.f},{0.f,0.f,0.f,0.f},
                     {0.f,0.f,0.f,0.f},{0.f,0.f,0.f,0.f}};

  for (int kb = 0; kb < K; kb += TILE_K) {
    float4 av = *(const float4*)&A[(size_t)(bm + la_r) * K + kb + la_c];
    float4 wv = *(const float4*)&W[(size_t)(kb + lw_r) * N + bn + lw_c];
    __syncthreads();
    As[la_c + 0][la_r] = av.x;
    As[la_c + 1][la_r] = av.y;
    As[la_c + 2][la_r] = av.z;
    As[la_c + 3][la_r] = av.w;
    *(float4*)&Ws[lw_r][lw_c] = wv;
    __syncthreads();
#pragma unroll
    for (int kk = 0; kk < TILE_K; ++kk) {
      float4 a = *(const float4*)&As[kk][tm];
      float4 b = *(const float4*)&Ws[kk][tn];
      acc[0][0] = fmaf(a.x, b.x, acc[0][0]);
      acc[0][1] = fmaf(a.x, b.y, acc[0][1]);
      acc[0][2] = fmaf(a.x, b.z, acc[0][2]);
      acc[0][3] = fmaf(a.x, b.w, acc[0][3]);
      acc[1][0] = fmaf(a.y, b.x, acc[1][0]);
      acc[1][1] = fmaf(a.y, b.y, acc[1][1]);
      acc[1][2] = fmaf(a.y, b.z, acc[1][2]);
      acc[1][3] = fmaf(a.y, b.w, acc[1][3]);
      acc[2][0] = fmaf(a.z, b.x, acc[2][0]);
      acc[2][1] = fmaf(a.z, b.y, acc[2][1]);
      acc[2][2] = fmaf(a.z, b.z, acc[2][2]);
      acc[2][3] = fmaf(a.z, b.w, acc[2][3]);
      acc[3][0] = fmaf(a.w, b.x, acc[3][0]);
      acc[3][1] = fmaf(a.w, b.y, acc[3][1]);
      acc[3][2] = fmaf(a.w, b.z, acc[3][2]);
      acc[3][3] = fmaf(a.w, b.w, acc[3][3]);
    }
  }

  const float* bias = sl.bias;
  float* out = sl.out;
  const int mode = sl.mode;
#pragma unroll
  for (int i = 0; i < 4; ++i) {
#pragma unroll
    for (int j = 0; j < 4; ++j) {
      int m = bm + tm + i, n = bn + tn + j;
      float c = acc[i][j] + bias[n];
      if (mode >= 1) c = silu_(c);
      if (mode == 2) {
        int h = n >> 6, d = n & 63;
        int b = m >> 10, l = m & 1023;
        out[(((size_t)(b * 16 + h)) * 1024 + l) * 64 + d] = c;
      } else {
        out[(size_t)m * N + n] = c;
      }
    }
  }
}

// ---------------------------------------------------------------------------
// Scalar projections, packed: scl[bh][t][8], slot 0=beta,1=fd,2=sd,3=fg,4=sg
// ---------------------------------------------------------------------------
__global__ __launch_bounds__(256) void scalar_proj(
    const float* __restrict__ hs,
    const float* __restrict__ Wb,  const float* __restrict__ bb,
    const float* __restrict__ Wfd, const float* __restrict__ bfd, const float* __restrict__ fdb,
    const float* __restrict__ Wsd, const float* __restrict__ bsd, const float* __restrict__ sdb,
    const float* __restrict__ Wfg, const float* __restrict__ bfg,
    const float* __restrict__ Wsg, const float* __restrict__ bsg,
    float* __restrict__ scl)
{
  int gid = blockIdx.x * 256 + threadIdx.x;  // < 2048*80
  int m = gid / 80;
  int c = gid - m * 80;
  int type = c >> 4;
  int h = c & 15;
  const float* W; const float* bias; float extra = 0.f;
  switch (type) {
    case 0:  W = Wb;  bias = bb;  break;
    case 1:  W = Wfd; bias = bfd; extra = fdb[h]; break;
    case 2:  W = Wsd; bias = bsd; extra = sdb[h]; break;
    case 3:  W = Wfg; bias = bfg; break;
    default: W = Wsg; bias = bsg; break;
  }
  const float* hrow = hs + (size_t)m * 1024;
  float s = 0.f;
  for (int k2 = 0; k2 < 1024; ++k2)
    s = fmaf(hrow[k2], W[k2 * 16 + h], s);
  s += bias[h] + extra;
  float r = sigm_(s);
  int b = m >> 10, l = m & 1023;
  scl[((size_t)((b * 16 + h) * 1024 + l)) * 8 + type] = r;
}

// ---------------------------------------------------------------------------
// Pre-normalize q and k in place: x *= rsqrt(sum_64(x^2)+1e-6).
// ---------------------------------------------------------------------------
__global__ __launch_bounds__(256) void prenorm(float* __restrict__ p)
{
  int wid = blockIdx.x * 4 + (threadIdx.x >> 6);
  int lane = threadIdx.x & 63;
  size_t idx = (size_t)wid * 64 + lane;
  float x = p[idx];
  float ss = x * x;
#pragma unroll
  for (int d2 = 32; d2 >= 1; d2 >>= 1) ss += __shfl_xor(ss, d2, 64);
  p[idx] = x * rsqrtf(ss + 1e-6f);
}

// ---------------------------------------------------------------------------
// Sequential scan, v11: 4 waves per (b,h), one fused pass + ONE RAW BARRIER
// per step. Two changes vs r10 (which was stall-bound, ~80% idle):
//  (1) __syncthreads -> s_waitcnt lgkmcnt(0) + s_barrier. The implicit
//      vmcnt(0) drain of __syncthreads was exposing ~600-900cyc of HBM
//      latency of the streaming k/q/v prefetches at EVERY step. LDS
//      visibility only needs lgkmcnt; global loads now stay in flight
//      across the barrier (HK/T4 pattern).
//  (2) pE/pG partials written RAW; the actual-scale factors afT/asT are
//      folded in at the READ side next step (carried in registers). The
//      ds_write no longer depends on the A-reduce->cap chain (~400cyc
//      off the pre-barrier critical path). Algebra identical to r10.
// ---------------------------------------------------------------------------
__global__ __launch_bounds__(256) void scan_kernel(
    const float* __restrict__ qg, const float* __restrict__ kg, const float* __restrict__ vg,
    const float* __restrict__ scl, const float* __restrict__ rfx, float* __restrict__ og)
{
  const int bh = blockIdx.x;     // 0..31
  const int tid = threadIdx.x;
  const int lane = tid & 63;     // column index
  const int w = tid >> 6;        // wave id: rows [16w, 16w+16)
  const float rf = rfx[0];
  const float rf2 = rf * rf;

  __shared__ float2 pE[2][4][64];  // {ef,es} partials (raw), double-buffered
  __shared__ float2 pG[2][4][64];  // {gf,gs} partials (raw)

  float Sf[16], Ss[16];
#pragma unroll
  for (int j = 0; j < 16; ++j) { Sf[j] = 0.f; Ss[j] = 0.f; }

  const float* kb = kg + (size_t)bh * 65536;
  const float* qb = qg + (size_t)bh * 65536;
  const float* vb = vg + (size_t)bh * 65536;
  const float* sb = scl + (size_t)bh * 8192;
  const int b = bh >> 4, h = bh & 15;
  float* ob = og + (size_t)b * (1024 * 1024) + h * 64;  // + t*1024 + lane

  // ---- prologue: t=0 inputs, qk_0, k_0 row broadcasts, step-0 coeffs ----
  float kv0 = kb[lane], qv0 = qb[lane];
  float kvA = kb[64 + lane], qvA = qb[64 + lane];   // t=1 per-lane
  float vv = vb[lane];
  float4 sc = *(const float4*)&sb[0];
  float sg4 = sb[4];

  float qkc = kv0 * qv0;
#pragma unroll
  for (int d2 = 32; d2 >= 1; d2 >>= 1) qkc += __shfl_xor(qkc, d2, 64);

  float kr[16];
#pragma unroll
  for (int j = 0; j < 16; ++j) kr[j] = rdl_(kv0, w * 16 + j);

  float braf, bras, cfs, csf;
  {
    const float raf = 1.f / sc.y;
    const float ras = 1.f / sc.z;
    braf = sc.x * raf;
    bras = sc.x * ras;
    cfs = rf * sc.z * raf;
    csf = rf * sc.y * ras;
  }

  float ef = 0.f, es = 0.f, gf = 0.f, gs = 0.f;   // dots vs zero state
  float Nf = 0.f, Ns = 0.f, Cc = 0.f;             // actual norms / cross
  float afTp = 1.f, asTp = 1.f;                   // carried read-side scales

  for (int t = 0; t < 1024; ++t) {
    const int t1 = (t + 1) & 1023;
    const int t2 = (t + 2) & 1023;

    // ---- RAW barrier: LDS visibility only, global loads stay in flight ----
    if (t > 0) {
      asm volatile("s_waitcnt lgkmcnt(0)" ::: "memory");
      __builtin_amdgcn_s_barrier();
    }

    // ---- prefetch right after barrier: k/q t+2, v/sc t+1 ----
    const float kvB = kb[t2 * 64 + lane];
    const float qvB = qb[t2 * 64 + lane];
    const float vn  = vb[t1 * 64 + lane];
    const float4 scn = *(const float4*)&sb[(size_t)t1 * 8];
    const float sgn = sb[(size_t)t1 * 8 + 4];

    // ---- read partials, fold carried actual-scale ----
    if (t > 0) {
      const int pr = (t - 1) & 1;
      float2 e0 = pE[pr][0][lane], e1 = pE[pr][1][lane];
      float2 e2 = pE[pr][2][lane], e3 = pE[pr][3][lane];
      float2 g0 = pG[pr][0][lane], g1 = pG[pr][1][lane];
      float2 g2 = pG[pr][2][lane], g3 = pG[pr][3][lane];
      ef = afTp * ((e0.x + e1.x) + (e2.x + e3.x));
      es = asTp * ((e0.y + e1.y) + (e2.y + e3.y));
      gf = afTp * ((g0.x + g1.x) + (g2.x + g3.x));
      gs = asTp * ((g0.y + g1.y) + (g2.y + g3.y));
    }

    // ---- qk for step t+1 (consumed next iteration) ----
    float qkn = kvA * qvA;
#pragma unroll
    for (int d2 = 32; d2 >= 1; d2 >>= 1) qkn += __shfl_xor(qkn, d2, 64);

    // ---- broadcast rows of k_{t+1}, q_{t+1} for the fused dots ----
    float kr1[16], qr1[16];
#pragma unroll
    for (int j = 0; j < 16; ++j) {
      kr1[j] = rdl_(kvA, w * 16 + j);
      qr1[j] = rdl_(qvA, w * 16 + j);
    }

    // ---- coefficients for step t+1 (div chain off critical path) ----
    const float rafn = 1.f / scn.y;
    const float rasn = 1.f / scn.z;
    const float brafn = scn.x * rafn;
    const float brasn = scn.x * rasn;
    const float cfsn = rf * scn.z * rafn;
    const float csfn = rf * scn.y * rasn;

    const float bt = sc.x, fdt = sc.y, sdt = sc.z, fgt = sc.w, sgt = sg4;

    // ---- head: decay (scalar), error, update coefficients ----
    const float EF = fdt * ef, ES = sdt * es;
    const float errf = vv - EF, errs = vv - ES;
    const float beff = braf * errf, bess = bras * errs;

    // ---- analytic output dots (exact) ----
    const float sfq = fmaf(qkc, beff, gf);   // q . Sf_updated (repr)
    const float svq = fmaf(qkc, bess, gs);
    const float of = fmaf(cfs, svq, sfq);    // q . Tf (repr)
    const float os = fmaf(csf, sfq, svq);

    // ---- A-reduce: 5 quadratic sums (overlaps the fused pass) ----
    float p1 = errf * errf, p2 = errs * errs, p3 = errf * errs;
    float p4 = vv * errf, p5 = vv * errs;
#pragma unroll
    for (int d2 = 32; d2 >= 1; d2 >>= 1) {
      p1 += __shfl_xor(p1, d2, 64);
      p2 += __shfl_xor(p2, d2, 64);
      p3 += __shfl_xor(p3, d2, 64);
      p4 += __shfl_xor(p4, d2, 64);
      p5 += __shfl_xor(p5, d2, 64);
    }

    // ---- single register pass: update + combine + fused t+1 dots ----
    float ef1 = 0.f, es1 = 0.f, gf1 = 0.f, gs1 = 0.f;
#pragma unroll
    for (int j = 0; j < 16; ++j) {
      float sfv = fmaf(kr[j], beff, Sf[j]);
      float svv = fmaf(kr[j], bess, Ss[j]);
      float tf = fmaf(cfs, svv, sfv);
      float ts = fmaf(csf, sfv, svv);
      ef1 = fmaf(kr1[j], tf, ef1);
      es1 = fmaf(kr1[j], ts, es1);
      gf1 = fmaf(qr1[j], tf, gf1);
      gs1 = fmaf(qr1[j], ts, gs1);
      Sf[j] = tf; Ss[j] = ts;
    }

    // ---- write RAW partials (no dependence on the norm chain) ----
    const int par = t & 1;
    pE[par][w][lane] = make_float2(ef1, es1);
    pG[par][w][lane] = make_float2(gf1, gs1);

    // ---- closed-form norm recurrences + cap ----
    const float A1 = p4 - p1, A2 = p5 - p2;
    const float A3 = p1, A4 = p2, A5 = p3;
    const float A67 = p4 + p5 - 2.f * p3;
    const float b2s = bt * bt;
    const float Nfd = fmaf(fdt * fdt, Nf, fmaf(2.f * bt, A1, b2s * A3));
    const float Nsd = fmaf(sdt * sdt, Ns, fmaf(2.f * bt, A2, b2s * A4));
    const float Cd  = fmaf(fdt * sdt, Cc, fmaf(bt, A67, b2s * A5));
    const float NTf = Nfd + 2.f * rf * Cd + rf2 * Nsd;
    const float NTs = Nsd + 2.f * rf * Cd + rf2 * Nfd;
    const float CT  = (1.f + rf2) * Cd + rf * (Nfd + Nsd);
    const bool capf = NTf > 4096.f;
    const bool caps = NTs > 4096.f;
    const float scf = capf ? 64.f * rsqrtf(NTf) : 1.f;
    const float scs = caps ? 64.f * rsqrtf(NTs) : 1.f;
    const float afT = fdt * scf;   // total repr->actual scale this step
    const float asT = sdt * scs;
    Nf = capf ? 4096.f : NTf;
    Ns = caps ? 4096.f : NTs;
    Cc = scf * scs * CT;

    // ---- output (actual scale) ----
    if (w == 0) ob[(size_t)t * 1024 + lane] = fgt * afT * of + sgt * asT * os;

    // ---- refold state to actual scale (partials folded at read) ----
#pragma unroll
    for (int j = 0; j < 16; ++j) { Sf[j] *= afT; Ss[j] *= asT; }

    // ---- rotate pipeline ----
#pragma unroll
    for (int j = 0; j < 16; ++j) kr[j] = kr1[j];
    kvA = kvB; qvA = qvB; vv = vn; sc = scn; sg4 = sgn; qkc = qkn;
    braf = brafn; bras = brasn; cfs = cfsn; csf = csfn;
    afTp = afT; asTp = asT;
  }
}

// ---------------------------------------------------------------------------
// Gated RMSNorm: og = o * rsqrt(mean(o^2)+eps) * onorm_w * silu_g (g pre-silu'd)
// ---------------------------------------------------------------------------
__global__ __launch_bounds__(256) void rms_gate(
    const float* __restrict__ o, const float* __restrict__ gsil,
    const float* __restrict__ onw, float* __restrict__ og)
{
  int gi = blockIdx.x * 4 + (threadIdx.x >> 6);
  int lane = threadIdx.x & 63;
  size_t idx = (size_t)gi * 64 + lane;
  float x = o[idx];
  float ss = x * x;
#pragma unroll
  for (int d2 = 32; d2 >= 1; d2 >>= 1) ss += __shfl_xor(ss, d2, 64);
  float r = rsqrtf(ss * (1.f / 64.f) + 1e-5f);
  og[idx] = x * r * onw[lane] * gsil[idx];
}

// ---------------------------------------------------------------------------
// Host launcher
// ---------------------------------------------------------------------------
extern "C" void kernel_launch(void* const* d_in, const int* in_sizes, int n_in,
                              void* d_out, int out_size, void* d_ws, size_t ws_size,
                              hipStream_t stream)
{
  const float* hs  = (const float*)d_in[0];
  const float* Wq  = (const float*)d_in[1];
  const float* bq  = (const float*)d_in[2];
  const float* Wk  = (const float*)d_in[3];
  const float* bk  = (const float*)d_in[4];
  const float* Wv  = (const float*)d_in[5];
  const float* bv  = (const float*)d_in[6];
  const float* Wb  = (const float*)d_in[7];
  const float* bb  = (const float*)d_in[8];
  const float* Wfd = (const float*)d_in[9];
  const float* bfd = (const float*)d_in[10];
  const float* fdb = (const float*)d_in[11];
  const float* Wsd = (const float*)d_in[12];
  const float* bsd = (const float*)d_in[13];
  const float* sdb = (const float*)d_in[14];
  const float* Wfg = (const float*)d_in[15];
  const float* bfg = (const float*)d_in[16];
  const float* Wsg = (const float*)d_in[17];
  const float* bsg = (const float*)d_in[18];
  const float* Wg  = (const float*)d_in[19];
  const float* bg  = (const float*)d_in[20];
  const float* onw = (const float*)d_in[21];
  const float* Wo  = (const float*)d_in[22];
  const float* bo  = (const float*)d_in[23];
  const float* rfx = (const float*)d_in[24];

  float* ws = (float*)d_ws;
  const size_t TWO_M = (size_t)1 << 21;  // 2M floats = B*H*L*64
  float* q_ws  = ws;                     // q and k contiguous for prenorm
  float* k_ws  = ws + TWO_M;
  float* v_ws  = ws + 2 * TWO_M;
  float* g_ws  = ws + 3 * TWO_M;
  float* o_ws  = ws + 4 * TWO_M;
  float* scl_ws = ws + 5 * TWO_M;        // 32*1024*8 floats packed scalars
  float* og_ws = q_ws;  // reuse q buffer (scan has consumed it)

  // 1) big projections: q,k,v (silu + scatter), g (silu, linear)
  GemmBatch gb1;
  gb1.s[0].W = Wq; gb1.s[0].bias = bq; gb1.s[0].out = q_ws; gb1.s[0].mode = 2;
  gb1.s[1].W = Wk; gb1.s[1].bias = bk; gb1.s[1].out = k_ws; gb1.s[1].mode = 2;
  gb1.s[2].W = Wv; gb1.s[2].bias = bv; gb1.s[2].out = v_ws; gb1.s[2].mode = 2;
  gb1.s[3].W = Wg; gb1.s[3].bias = bg; gb1.s[3].out = g_ws; gb1.s[3].mode = 1;
  gemm_act<<<dim3(32, 16, 4), 256, 0, stream>>>(hs, gb1, 2048, 1024, 1024);

  // 2) per-head scalar projections (packed)
  scalar_proj<<<640, 256, 0, stream>>>(hs, Wb, bb, Wfd, bfd, fdb, Wsd, bsd, sdb,
                                       Wfg, bfg, Wsg, bsg, scl_ws);

  // 3) pre-normalize q,k (contiguous 4M floats = 65536 rows of 64)
  prenorm<<<16384, 256, 0, stream>>>(q_ws);

  // 4) sequential dual-state delta-rule scan: 4 waves, raw barrier
  scan_kernel<<<32, 256, 0, stream>>>(q_ws, k_ws, v_ws, scl_ws, rfx, o_ws);

  // 5) gated RMSNorm
  rms_gate<<<8192, 256, 0, stream>>>(o_ws, g_ws, onw, og_ws);

  // 6) output projection -> d_out
  GemmBatch gb2;
  gb2.s[0].W = Wo; gb2.s[0].bias = bo; gb2.s[0].out = (float*)d_out; gb2.s[0].mode = 0;
  gb2.s[1] = gb2.s[0]; gb2.s[2] = gb2.s[0]; gb2.s[3] = gb2.s[0];
  gemm_act<<<dim3(32, 16, 1), 256, 0, stream>>>(og_ws, gb2, 2048, 1024, 1024);
}

// Round 12
// 1620.717 us; speedup vs baseline: 1.0494x; 1.0385x over previous
//
#include <hip/hip_runtime.h>

// ---------------------------------------------------------------------------
// Problem constants: B=2, L=1024, D=1024, H=16, DK=DV=64
// ---------------------------------------------------------------------------

#define TILE_M 64
#define TILE_N 64
#define TILE_K 16

struct GemmSlot { const float* W; const float* bias; float* out; int mode; };
struct GemmBatch { GemmSlot s[4]; };

__device__ __forceinline__ float silu_(float x) {
  return x / (1.f + __expf(-x));
}
__device__ __forceinline__ float sigm_(float x) {
  return 1.f / (1.f + __expf(-x));
}
__device__ __forceinline__ float rdl_(float v, int l) {
  return __int_as_float(__builtin_amdgcn_readlane(__float_as_int(v), l));
}

// ---------------------------------------------------------------------------
// Generic fp32 GEMM: C = act(A[M,K] @ W[K,N] + bias), act/store per mode.
// mode 0: raw, linear store; mode 1: silu, linear; mode 2: silu, scatter BHLd
// ---------------------------------------------------------------------------
__global__ __launch_bounds__(256) void gemm_act(
    const float* __restrict__ A, GemmBatch gb, int M, int N, int K)
{
  const GemmSlot sl = gb.s[blockIdx.z];
  const float* __restrict__ W = sl.W;

  __shared__ float As[TILE_K][TILE_M + 4];
  __shared__ float Ws[TILE_K][TILE_N];

  const int tid = threadIdx.x;
  const int bm = blockIdx.x * TILE_M;
  const int bn = blockIdx.y * TILE_N;
  const int tm = (tid >> 4) << 2;
  const int tn = (tid & 15) << 2;
  const int la_r = tid >> 2;
  const int la_c = (tid & 3) << 2;
  const int lw_r = tid >> 4;
  const int lw_c = (tid & 15) << 2;

  float acc[4][4] = {{0.f,0.f,0.f,0.f},{0.f,0.f,0.f,0.f},
                     {0.f,0.f,0.f,0.f},{0.f,0.f,0.f,0.f}};

  for (int kb = 0; kb < K; kb += TILE_K) {
    float4 av = *(const float4*)&A[(size_t)(bm + la_r) * K + kb + la_c];
    float4 wv = *(const float4*)&W[(size_t)(kb + lw_r) * N + bn + lw_c];
    __syncthreads();
    As[la_c + 0][la_r] = av.x;
    As[la_c + 1][la_r] = av.y;
    As[la_c + 2][la_r] = av.z;
    As[la_c + 3][la_r] = av.w;
    *(float4*)&Ws[lw_r][lw_c] = wv;
    __syncthreads();
#pragma unroll
    for (int kk = 0; kk < TILE_K; ++kk) {
      float4 a = *(const float4*)&As[kk][tm];
      float4 b = *(const float4*)&Ws[kk][tn];
      acc[0][0] = fmaf(a.x, b.x, acc[0][0]);
      acc[0][1] = fmaf(a.x, b.y, acc[0][1]);
      acc[0][2] = fmaf(a.x, b.z, acc[0][2]);
      acc[0][3] = fmaf(a.x, b.w, acc[0][3]);
      acc[1][0] = fmaf(a.y, b.x, acc[1][0]);
      acc[1][1] = fmaf(a.y, b.y, acc[1][1]);
      acc[1][2] = fmaf(a.y, b.z, acc[1][2]);
      acc[1][3] = fmaf(a.y, b.w, acc[1][3]);
      acc[2][0] = fmaf(a.z, b.x, acc[2][0]);
      acc[2][1] = fmaf(a.z, b.y, acc[2][1]);
      acc[2][2] = fmaf(a.z, b.z, acc[2][2]);
      acc[2][3] = fmaf(a.z, b.w, acc[2][3]);
      acc[3][0] = fmaf(a.w, b.x, acc[3][0]);
      acc[3][1] = fmaf(a.w, b.y, acc[3][1]);
      acc[3][2] = fmaf(a.w, b.z, acc[3][2]);
      acc[3][3] = fmaf(a.w, b.w, acc[3][3]);
    }
  }

  const float* bias = sl.bias;
  float* out = sl.out;
  const int mode = sl.mode;
#pragma unroll
  for (int i = 0; i < 4; ++i) {
#pragma unroll
    for (int j = 0; j < 4; ++j) {
      int m = bm + tm + i, n = bn + tn + j;
      float c = acc[i][j] + bias[n];
      if (mode >= 1) c = silu_(c);
      if (mode == 2) {
        int h = n >> 6, d = n & 63;
        int b = m >> 10, l = m & 1023;
        out[(((size_t)(b * 16 + h)) * 1024 + l) * 64 + d] = c;
      } else {
        out[(size_t)m * N + n] = c;
      }
    }
  }
}

// ---------------------------------------------------------------------------
// Scalar projections, packed: scl[bh][t][8], slot 0=beta,1=fd,2=sd,3=fg,4=sg
// ---------------------------------------------------------------------------
__global__ __launch_bounds__(256) void scalar_proj(
    const float* __restrict__ hs,
    const float* __restrict__ Wb,  const float* __restrict__ bb,
    const float* __restrict__ Wfd, const float* __restrict__ bfd, const float* __restrict__ fdb,
    const float* __restrict__ Wsd, const float* __restrict__ bsd, const float* __restrict__ sdb,
    const float* __restrict__ Wfg, const float* __restrict__ bfg,
    const float* __restrict__ Wsg, const float* __restrict__ bsg,
    float* __restrict__ scl)
{
  int gid = blockIdx.x * 256 + threadIdx.x;  // < 2048*80
  int m = gid / 80;
  int c = gid - m * 80;
  int type = c >> 4;
  int h = c & 15;
  const float* W; const float* bias; float extra = 0.f;
  switch (type) {
    case 0:  W = Wb;  bias = bb;  break;
    case 1:  W = Wfd; bias = bfd; extra = fdb[h]; break;
    case 2:  W = Wsd; bias = bsd; extra = sdb[h]; break;
    case 3:  W = Wfg; bias = bfg; break;
    default: W = Wsg; bias = bsg; break;
  }
  const float* hrow = hs + (size_t)m * 1024;
  float s = 0.f;
  for (int k2 = 0; k2 < 1024; ++k2)
    s = fmaf(hrow[k2], W[k2 * 16 + h], s);
  s += bias[h] + extra;
  float r = sigm_(s);
  int b = m >> 10, l = m & 1023;
  scl[((size_t)((b * 16 + h) * 1024 + l)) * 8 + type] = r;
}

// ---------------------------------------------------------------------------
// Pre-normalize q and k in place: x *= rsqrt(sum_64(x^2)+1e-6).
// ---------------------------------------------------------------------------
__global__ __launch_bounds__(256) void prenorm(float* __restrict__ p)
{
  int wid = blockIdx.x * 4 + (threadIdx.x >> 6);
  int lane = threadIdx.x & 63;
  size_t idx = (size_t)wid * 64 + lane;
  float x = p[idx];
  float ss = x * x;
#pragma unroll
  for (int d2 = 32; d2 >= 1; d2 >>= 1) ss += __shfl_xor(ss, d2, 64);
  p[idx] = x * rsqrtf(ss + 1e-6f);
}

// ---------------------------------------------------------------------------
// Sequential scan, v12: EIGHT waves per (b,h) (512-thread block, 32 blocks)
// -> 8 waves/CU = 2 waves/SIMD. r8-r11 were stall-bound at 1 wave/SIMD
// (~1900cyc/step exposed shfl/LDS/barrier latency); two co-resident waves
// interleave so one wave's ds_bpermute/ds_read stalls absorb the other's
// issue. Per-wave state is tiny (rows [8w,8w+8): Sf[8],Ss[8] ~90 VGPR)
// so the r7 register-budget failure cannot recur.
// Also: A-reduce pre-combined with uniform bt into THREE per-lane values
// (x1,x2,x3) -> 18 shfls instead of 30, same recurrence inputs.
// Structure otherwise = r11: fused next-step dots, one raw barrier
// (lgkmcnt-only), raw partials folded by carried afTp/asTp at read.
// ---------------------------------------------------------------------------
__global__ __launch_bounds__(512) void scan_kernel(
    const float* __restrict__ qg, const float* __restrict__ kg, const float* __restrict__ vg,
    const float* __restrict__ scl, const float* __restrict__ rfx, float* __restrict__ og)
{
  const int bh = blockIdx.x;     // 0..31
  const int tid = threadIdx.x;
  const int lane = tid & 63;     // column index
  const int w = tid >> 6;        // wave id 0..7: rows [8w, 8w+8)
  const float rf = rfx[0];
  const float rf2 = rf * rf;

  __shared__ float2 pE[2][8][64];  // {ef,es} partials (raw), double-buffered
  __shared__ float2 pG[2][8][64];  // {gf,gs} partials (raw)

  float Sf[8], Ss[8];
#pragma unroll
  for (int j = 0; j < 8; ++j) { Sf[j] = 0.f; Ss[j] = 0.f; }

  const float* kb = kg + (size_t)bh * 65536;
  const float* qb = qg + (size_t)bh * 65536;
  const float* vb = vg + (size_t)bh * 65536;
  const float* sb = scl + (size_t)bh * 8192;
  const int b = bh >> 4, h = bh & 15;
  float* ob = og + (size_t)b * (1024 * 1024) + h * 64;  // + t*1024 + lane

  // ---- prologue: t=0 inputs, qk_0, k_0 row broadcasts, step-0 coeffs ----
  float kv0 = kb[lane], qv0 = qb[lane];
  float kvA = kb[64 + lane], qvA = qb[64 + lane];   // t=1 per-lane
  float vv = vb[lane];
  float4 sc = *(const float4*)&sb[0];
  float sg4 = sb[4];

  float qkc = kv0 * qv0;
#pragma unroll
  for (int d2 = 32; d2 >= 1; d2 >>= 1) qkc += __shfl_xor(qkc, d2, 64);

  float kr[8];
#pragma unroll
  for (int j = 0; j < 8; ++j) kr[j] = rdl_(kv0, w * 8 + j);

  float braf, bras, cfs, csf;
  {
    const float raf = 1.f / sc.y;
    const float ras = 1.f / sc.z;
    braf = sc.x * raf;
    bras = sc.x * ras;
    cfs = rf * sc.z * raf;
    csf = rf * sc.y * ras;
  }

  float ef = 0.f, es = 0.f, gf = 0.f, gs = 0.f;   // dots vs zero state
  float Nf = 0.f, Ns = 0.f, Cc = 0.f;             // actual norms / cross
  float afTp = 1.f, asTp = 1.f;                   // carried read-side scales

  for (int t = 0; t < 1024; ++t) {
    const int t1 = (t + 1) & 1023;
    const int t2 = (t + 2) & 1023;

    // ---- RAW barrier: LDS visibility only, global loads stay in flight ----
    if (t > 0) {
      asm volatile("s_waitcnt lgkmcnt(0)" ::: "memory");
      __builtin_amdgcn_s_barrier();
    }

    // ---- prefetch right after barrier: k/q t+2, v/sc t+1 ----
    const float kvB = kb[t2 * 64 + lane];
    const float qvB = qb[t2 * 64 + lane];
    const float vn  = vb[t1 * 64 + lane];
    const float4 scn = *(const float4*)&sb[(size_t)t1 * 8];
    const float sgn = sb[(size_t)t1 * 8 + 4];

    // ---- read partials (8 waves), fold carried actual-scale ----
    if (t > 0) {
      const int pr = (t - 1) & 1;
      float2 e0 = pE[pr][0][lane], e1 = pE[pr][1][lane];
      float2 e2 = pE[pr][2][lane], e3 = pE[pr][3][lane];
      float2 e4 = pE[pr][4][lane], e5 = pE[pr][5][lane];
      float2 e6 = pE[pr][6][lane], e7 = pE[pr][7][lane];
      float2 g0 = pG[pr][0][lane], g1 = pG[pr][1][lane];
      float2 g2 = pG[pr][2][lane], g3 = pG[pr][3][lane];
      float2 g4 = pG[pr][4][lane], g5 = pG[pr][5][lane];
      float2 g6 = pG[pr][6][lane], g7 = pG[pr][7][lane];
      ef = afTp * (((e0.x + e1.x) + (e2.x + e3.x)) + ((e4.x + e5.x) + (e6.x + e7.x)));
      es = asTp * (((e0.y + e1.y) + (e2.y + e3.y)) + ((e4.y + e5.y) + (e6.y + e7.y)));
      gf = afTp * (((g0.x + g1.x) + (g2.x + g3.x)) + ((g4.x + g5.x) + (g6.x + g7.x)));
      gs = asTp * (((g0.y + g1.y) + (g2.y + g3.y)) + ((g4.y + g5.y) + (g6.y + g7.y)));
    }

    // ---- qk for step t+1 (consumed next iteration) ----
    float qkn = kvA * qvA;
#pragma unroll
    for (int d2 = 32; d2 >= 1; d2 >>= 1) qkn += __shfl_xor(qkn, d2, 64);

    // ---- broadcast rows of k_{t+1}, q_{t+1} for the fused dots ----
    float kr1[8], qr1[8];
#pragma unroll
    for (int j = 0; j < 8; ++j) {
      kr1[j] = rdl_(kvA, w * 8 + j);
      qr1[j] = rdl_(qvA, w * 8 + j);
    }

    // ---- coefficients for step t+1 (div chain off critical path) ----
    const float rafn = 1.f / scn.y;
    const float rasn = 1.f / scn.z;
    const float brafn = scn.x * rafn;
    const float brasn = scn.x * rasn;
    const float cfsn = rf * scn.z * rafn;
    const float csfn = rf * scn.y * rasn;

    const float bt = sc.x, fdt = sc.y, sdt = sc.z, fgt = sc.w, sgt = sg4;

    // ---- head: decay (scalar), error, update coefficients ----
    const float EF = fdt * ef, ES = sdt * es;
    const float errf = vv - EF, errs = vv - ES;
    const float beff = braf * errf, bess = bras * errs;

    // ---- analytic output dots (exact) ----
    const float sfq = fmaf(qkc, beff, gf);   // q . Sf_updated (repr)
    const float svq = fmaf(qkc, bess, gs);
    const float of = fmaf(cfs, svq, sfq);    // q . Tf (repr)
    const float os = fmaf(csf, sfq, svq);

    // ---- A-reduce: 3 pre-combined values (bt uniform) ----
    // x1 = 2bt*errf*EF + bt^2*errf^2 ; x2 likewise ; x3 = Cd increment
    float x1 = bt * errf * fmaf(bt, errf, 2.f * EF);
    float x2 = bt * errs * fmaf(bt, errs, 2.f * ES);
    float x3 = bt * (fmaf(bt, errf * errs, errs * EF) + errf * ES);
#pragma unroll
    for (int d2 = 32; d2 >= 1; d2 >>= 1) {
      x1 += __shfl_xor(x1, d2, 64);
      x2 += __shfl_xor(x2, d2, 64);
      x3 += __shfl_xor(x3, d2, 64);
    }

    // ---- single register pass: update + combine + fused t+1 dots ----
    float ef1 = 0.f, es1 = 0.f, gf1 = 0.f, gs1 = 0.f;
#pragma unroll
    for (int j = 0; j < 8; ++j) {
      float sfv = fmaf(kr[j], beff, Sf[j]);
      float svv = fmaf(kr[j], bess, Ss[j]);
      float tf = fmaf(cfs, svv, sfv);
      float ts = fmaf(csf, sfv, svv);
      ef1 = fmaf(kr1[j], tf, ef1);
      es1 = fmaf(kr1[j], ts, es1);
      gf1 = fmaf(qr1[j], tf, gf1);
      gs1 = fmaf(qr1[j], ts, gs1);
      Sf[j] = tf; Ss[j] = ts;
    }

    // ---- write RAW partials (no dependence on the norm chain) ----
    const int par = t & 1;
    pE[par][w][lane] = make_float2(ef1, es1);
    pG[par][w][lane] = make_float2(gf1, gs1);

    // ---- closed-form norm recurrences + cap ----
    const float Nfd = fmaf(fdt * fdt, Nf, x1);
    const float Nsd = fmaf(sdt * sdt, Ns, x2);
    const float Cd  = fmaf(fdt * sdt, Cc, x3);
    const float NTf = Nfd + 2.f * rf * Cd + rf2 * Nsd;
    const float NTs = Nsd + 2.f * rf * Cd + rf2 * Nfd;
    const float CT  = (1.f + rf2) * Cd + rf * (Nfd + Nsd);
    const bool capf = NTf > 4096.f;
    const bool caps = NTs > 4096.f;
    const float scf = capf ? 64.f * rsqrtf(NTf) : 1.f;
    const float scs = caps ? 64.f * rsqrtf(NTs) : 1.f;
    const float afT = fdt * scf;   // total repr->actual scale this step
    const float asT = sdt * scs;
    Nf = capf ? 4096.f : NTf;
    Ns = caps ? 4096.f : NTs;
    Cc = scf * scs * CT;

    // ---- output (actual scale) ----
    if (w == 0) ob[(size_t)t * 1024 + lane] = fgt * afT * of + sgt * asT * os;

    // ---- refold state to actual scale (partials folded at read) ----
#pragma unroll
    for (int j = 0; j < 8; ++j) { Sf[j] *= afT; Ss[j] *= asT; }

    // ---- rotate pipeline ----
#pragma unroll
    for (int j = 0; j < 8; ++j) kr[j] = kr1[j];
    kvA = kvB; qvA = qvB; vv = vn; sc = scn; sg4 = sgn; qkc = qkn;
    braf = brafn; bras = brasn; cfs = cfsn; csf = csfn;
    afTp = afT; asTp = asT;
  }
}

// ---------------------------------------------------------------------------
// Gated RMSNorm: og = o * rsqrt(mean(o^2)+eps) * onorm_w * silu_g (g pre-silu'd)
// ---------------------------------------------------------------------------
__global__ __launch_bounds__(256) void rms_gate(
    const float* __restrict__ o, const float* __restrict__ gsil,
    const float* __restrict__ onw, float* __restrict__ og)
{
  int gi = blockIdx.x * 4 + (threadIdx.x >> 6);
  int lane = threadIdx.x & 63;
  size_t idx = (size_t)gi * 64 + lane;
  float x = o[idx];
  float ss = x * x;
#pragma unroll
  for (int d2 = 32; d2 >= 1; d2 >>= 1) ss += __shfl_xor(ss, d2, 64);
  float r = rsqrtf(ss * (1.f / 64.f) + 1e-5f);
  og[idx] = x * r * onw[lane] * gsil[idx];
}

// ---------------------------------------------------------------------------
// Host launcher
// ---------------------------------------------------------------------------
extern "C" void kernel_launch(void* const* d_in, const int* in_sizes, int n_in,
                              void* d_out, int out_size, void* d_ws, size_t ws_size,
                              hipStream_t stream)
{
  const float* hs  = (const float*)d_in[0];
  const float* Wq  = (const float*)d_in[1];
  const float* bq  = (const float*)d_in[2];
  const float* Wk  = (const float*)d_in[3];
  const float* bk  = (const float*)d_in[4];
  const float* Wv  = (const float*)d_in[5];
  const float* bv  = (const float*)d_in[6];
  const float* Wb  = (const float*)d_in[7];
  const float* bb  = (const float*)d_in[8];
  const float* Wfd = (const float*)d_in[9];
  const float* bfd = (const float*)d_in[10];
  const float* fdb = (const float*)d_in[11];
  const float* Wsd = (const float*)d_in[12];
  const float* bsd = (const float*)d_in[13];
  const float* sdb = (const float*)d_in[14];
  const float* Wfg = (const float*)d_in[15];
  const float* bfg = (const float*)d_in[16];
  const float* Wsg = (const float*)d_in[17];
  const float* bsg = (const float*)d_in[18];
  const float* Wg  = (const float*)d_in[19];
  const float* bg  = (const float*)d_in[20];
  const float* onw = (const float*)d_in[21];
  const float* Wo  = (const float*)d_in[22];
  const float* bo  = (const float*)d_in[23];
  const float* rfx = (const float*)d_in[24];

  float* ws = (float*)d_ws;
  const size_t TWO_M = (size_t)1 << 21;  // 2M floats = B*H*L*64
  float* q_ws  = ws;                     // q and k contiguous for prenorm
  float* k_ws  = ws + TWO_M;
  float* v_ws  = ws + 2 * TWO_M;
  float* g_ws  = ws + 3 * TWO_M;
  float* o_ws  = ws + 4 * TWO_M;
  float* scl_ws = ws + 5 * TWO_M;        // 32*1024*8 floats packed scalars
  float* og_ws = q_ws;  // reuse q buffer (scan has consumed it)

  // 1) big projections: q,k,v (silu + scatter), g (silu, linear)
  GemmBatch gb1;
  gb1.s[0].W = Wq; gb1.s[0].bias = bq; gb1.s[0].out = q_ws; gb1.s[0].mode = 2;
  gb1.s[1].W = Wk; gb1.s[1].bias = bk; gb1.s[1].out = k_ws; gb1.s[1].mode = 2;
  gb1.s[2].W = Wv; gb1.s[2].bias = bv; gb1.s[2].out = v_ws; gb1.s[2].mode = 2;
  gb1.s[3].W = Wg; gb1.s[3].bias = bg; gb1.s[3].out = g_ws; gb1.s[3].mode = 1;
  gemm_act<<<dim3(32, 16, 4), 256, 0, stream>>>(hs, gb1, 2048, 1024, 1024);

  // 2) per-head scalar projections (packed)
  scalar_proj<<<640, 256, 0, stream>>>(hs, Wb, bb, Wfd, bfd, fdb, Wsd, bsd, sdb,
                                       Wfg, bfg, Wsg, bsg, scl_ws);

  // 3) pre-normalize q,k (contiguous 4M floats = 65536 rows of 64)
  prenorm<<<16384, 256, 0, stream>>>(q_ws);

  // 4) sequential dual-state delta-rule scan: 8 waves/bh, 2 waves/SIMD
  scan_kernel<<<32, 512, 0, stream>>>(q_ws, k_ws, v_ws, scl_ws, rfx, o_ws);

  // 5) gated RMSNorm
  rms_gate<<<8192, 256, 0, stream>>>(o_ws, g_ws, onw, og_ws);

  // 6) output projection -> d_out
  GemmBatch gb2;
  gb2.s[0].W = Wo; gb2.s[0].bias = bo; gb2.s[0].out = (float*)d_out; gb2.s[0].mode = 0;
  gb2.s[1] = gb2.s[0]; gb2.s[2] = gb2.s[0]; gb2.s[3] = gb2.s[0];
  gemm_act<<<dim3(32, 16, 1), 256, 0, stream>>>(og_ws, gb2, 2048, 1024, 1024);
}

// Round 13
// 1438.847 us; speedup vs baseline: 1.1821x; 1.1264x over previous
//
#include <hip/hip_runtime.h>

// ---------------------------------------------------------------------------
// Problem constants: B=2, L=1024, D=1024, H=16, DK=DV=64
// ---------------------------------------------------------------------------

#define TILE_M 64
#define TILE_N 64
#define TILE_K 16

struct GemmSlot { const float* W; const float* bias; float* out; int mode; };
struct GemmBatch { GemmSlot s[4]; };

__device__ __forceinline__ float silu_(float x) {
  return x / (1.f + __expf(-x));
}
__device__ __forceinline__ float sigm_(float x) {
  return 1.f / (1.f + __expf(-x));
}
__device__ __forceinline__ float rdl_(float v, int l) {
  return __int_as_float(__builtin_amdgcn_readlane(__float_as_int(v), l));
}

// ---------------------------------------------------------------------------
// Generic fp32 GEMM: C = act(A[M,K] @ W[K,N] + bias), act/store per mode.
// mode 0: raw, linear store; mode 1: silu, linear; mode 2: silu, scatter BHLd
// ---------------------------------------------------------------------------
__global__ __launch_bounds__(256) void gemm_act(
    const float* __restrict__ A, GemmBatch gb, int M, int N, int K)
{
  const GemmSlot sl = gb.s[blockIdx.z];
  const float* __restrict__ W = sl.W;

  __shared__ float As[TILE_K][TILE_M + 4];
  __shared__ float Ws[TILE_K][TILE_N];

  const int tid = threadIdx.x;
  const int bm = blockIdx.x * TILE_M;
  const int bn = blockIdx.y * TILE_N;
  const int tm = (tid >> 4) << 2;
  const int tn = (tid & 15) << 2;
  const int la_r = tid >> 2;
  const int la_c = (tid & 3) << 2;
  const int lw_r = tid >> 4;
  const int lw_c = (tid & 15) << 2;

  float acc[4][4] = {{0.f,0.f,0.f,0.f},{0.f,0.f,0.f,0.f},
                     {0.f,0.f,0.f,0.f},{0.f,0.f,0.f,0.f}};

  for (int kb = 0; kb < K; kb += TILE_K) {
    float4 av = *(const float4*)&A[(size_t)(bm + la_r) * K + kb + la_c];
    float4 wv = *(const float4*)&W[(size_t)(kb + lw_r) * N + bn + lw_c];
    __syncthreads();
    As[la_c + 0][la_r] = av.x;
    As[la_c + 1][la_r] = av.y;
    As[la_c + 2][la_r] = av.z;
    As[la_c + 3][la_r] = av.w;
    *(float4*)&Ws[lw_r][lw_c] = wv;
    __syncthreads();
#pragma unroll
    for (int kk = 0; kk < TILE_K; ++kk) {
      float4 a = *(const float4*)&As[kk][tm];
      float4 b = *(const float4*)&Ws[kk][tn];
      acc[0][0] = fmaf(a.x, b.x, acc[0][0]);
      acc[0][1] = fmaf(a.x, b.y, acc[0][1]);
      acc[0][2] = fmaf(a.x, b.z, acc[0][2]);
      acc[0][3] = fmaf(a.x, b.w, acc[0][3]);
      acc[1][0] = fmaf(a.y, b.x, acc[1][0]);
      acc[1][1] = fmaf(a.y, b.y, acc[1][1]);
      acc[1][2] = fmaf(a.y, b.z, acc[1][2]);
      acc[1][3] = fmaf(a.y, b.w, acc[1][3]);
      acc[2][0] = fmaf(a.z, b.x, acc[2][0]);
      acc[2][1] = fmaf(a.z, b.y, acc[2][1]);
      acc[2][2] = fmaf(a.z, b.z, acc[2][2]);
      acc[2][3] = fmaf(a.z, b.w, acc[2][3]);
      acc[3][0] = fmaf(a.w, b.x, acc[3][0]);
      acc[3][1] = fmaf(a.w, b.y, acc[3][1]);
      acc[3][2] = fmaf(a.w, b.z, acc[3][2]);
      acc[3][3] = fmaf(a.w, b.w, acc[3][3]);
    }
  }

  const float* bias = sl.bias;
  float* out = sl.out;
  const int mode = sl.mode;
#pragma unroll
  for (int i = 0; i < 4; ++i) {
#pragma unroll
    for (int j = 0; j < 4; ++j) {
      int m = bm + tm + i, n = bn + tn + j;
      float c = acc[i][j] + bias[n];
      if (mode >= 1) c = silu_(c);
      if (mode == 2) {
        int h = n >> 6, d = n & 63;
        int b = m >> 10, l = m & 1023;
        out[(((size_t)(b * 16 + h)) * 1024 + l) * 64 + d] = c;
      } else {
        out[(size_t)m * N + n] = c;
      }
    }
  }
}

// ---------------------------------------------------------------------------
// Scalar projections v2: LDS-tiled. Block stages 8 hs rows (32.9KB LDS),
// threads compute 640 dot-products (8 rows x 80 outputs) with float4 hs
// reads (LDS broadcast) and L2-resident W. scl[bh][t][8] packing as before.
// ---------------------------------------------------------------------------
__global__ __launch_bounds__(256) void scalar_proj(
    const float* __restrict__ hs,
    const float* __restrict__ Wb,  const float* __restrict__ bb,
    const float* __restrict__ Wfd, const float* __restrict__ bfd, const float* __restrict__ fdb,
    const float* __restrict__ Wsd, const float* __restrict__ bsd, const float* __restrict__ sdb,
    const float* __restrict__ Wfg, const float* __restrict__ bfg,
    const float* __restrict__ Wsg, const float* __restrict__ bsg,
    float* __restrict__ scl)
{
  __shared__ float hl[8][1028];
  const int tid = threadIdx.x;
  const int m0 = blockIdx.x * 8;

#pragma unroll
  for (int i = 0; i < 8; ++i) {
    int f = tid + 256 * i;        // 0..2047 float4s
    int r = f >> 8;
    int c4 = f & 255;
    float4 v = *(const float4*)&hs[(size_t)(m0 + r) * 1024 + c4 * 4];
    *(float4*)&hl[r][c4 * 4] = v;
  }
  __syncthreads();

  for (int c = 0; c < 3; ++c) {
    int o = tid + 256 * c;
    if (o >= 640) break;
    int ml = o / 80;
    int cc = o - ml * 80;
    int type = cc >> 4;
    int h = cc & 15;
    const float* W; const float* bias; float extra = 0.f;
    switch (type) {
      case 0:  W = Wb;  bias = bb;  break;
      case 1:  W = Wfd; bias = bfd; extra = fdb[h]; break;
      case 2:  W = Wsd; bias = bsd; extra = sdb[h]; break;
      case 3:  W = Wfg; bias = bfg; break;
      default: W = Wsg; bias = bsg; break;
    }
    float s = 0.f;
    for (int k = 0; k < 1024; k += 4) {
      float4 hv = *(const float4*)&hl[ml][k];
      s = fmaf(hv.x, W[(k + 0) * 16 + h], s);
      s = fmaf(hv.y, W[(k + 1) * 16 + h], s);
      s = fmaf(hv.z, W[(k + 2) * 16 + h], s);
      s = fmaf(hv.w, W[(k + 3) * 16 + h], s);
    }
    s += bias[h] + extra;
    int m = m0 + ml;
    int b = m >> 10, l = m & 1023;
    scl[((size_t)((b * 16 + h) * 1024 + l)) * 8 + type] = sigm_(s);
  }
}

// ---------------------------------------------------------------------------
// Pre-normalize q and k in place: x *= rsqrt(sum_64(x^2)+1e-6).
// ---------------------------------------------------------------------------
__global__ __launch_bounds__(256) void prenorm(float* __restrict__ p)
{
  int wid = blockIdx.x * 4 + (threadIdx.x >> 6);
  int lane = threadIdx.x & 63;
  size_t idx = (size_t)wid * 64 + lane;
  float x = p[idx];
  float ss = x * x;
#pragma unroll
  for (int d2 = 32; d2 >= 1; d2 >>= 1) ss += __shfl_xor(ss, d2, 64);
  p[idx] = x * rsqrtf(ss + 1e-6f);
}

// ---------------------------------------------------------------------------
// Sequential scan, v13: 8 waves x 8 rows, one raw barrier per step, with the
// ENTIRE norm/cap chain taken off the critical path:
//  - lazy-alpha: state stays repr-scale; cap scale scf_t is computed at step
//    t+1 (x-shfl chain spans the barrier, zero exposed latency) and folded
//    into the carried alpha. Output for step t is deferred to t+1.
//  - wave specialization: only wave 0 runs the 18-op x-shfl-reduce (publishes
//    reduced x1,x2,x3 via a 16B LDS slot); only wave 1 runs the qk-reduce and
//    writes the output. LDS-pipe ops/step drop ~290 -> ~185.
//  - refold to actual scale every 8 steps (alpha >= (0.15)^8 ~ 2.6e-7; repr
//    magnitudes <= ~1e9, fp32-safe). Fold applies to state, outgoing
//    partials, and the deferred output dots. Algebra exact vs r12 (passed).
// ---------------------------------------------------------------------------
__global__ __launch_bounds__(512) void scan_kernel(
    const float* __restrict__ qg, const float* __restrict__ kg, const float* __restrict__ vg,
    const float* __restrict__ scl, const float* __restrict__ rfx, float* __restrict__ og)
{
  const int bh = blockIdx.x;     // 0..31
  const int tid = threadIdx.x;
  const int lane = tid & 63;     // column index
  const int w = tid >> 6;        // wave id 0..7: rows [8w, 8w+8)
  const float rf = rfx[0];
  const float rf2 = rf * rf;

  __shared__ float2 pE[2][8][64];  // {ef,es} partials, double-buffered
  __shared__ float2 pG[2][8][64];  // {gf,gs} partials
  __shared__ float4 xb[2];         // reduced x1,x2,x3 from wave 0

  float Sf[8], Ss[8];
#pragma unroll
  for (int j = 0; j < 8; ++j) { Sf[j] = 0.f; Ss[j] = 0.f; }

  const float* kb = kg + (size_t)bh * 65536;
  const float* qb = qg + (size_t)bh * 65536;
  const float* vb = vg + (size_t)bh * 65536;
  const float* sb = scl + (size_t)bh * 8192;
  const int b = bh >> 4, h = bh & 15;
  float* ob = og + (size_t)b * (1024 * 1024) + h * 64;  // + t*1024 + lane

  // ---- prologue ----
  float kv0 = kb[lane], qv0 = qb[lane];
  float kvA = kb[64 + lane], qvA = qb[64 + lane];   // t=1 per-lane
  float vv = vb[lane];
  float4 sc = *(const float4*)&sb[0];
  float sg4 = sb[4];

  float kr[8];
#pragma unroll
  for (int j = 0; j < 8; ++j) kr[j] = rdl_(kv0, w * 8 + j);

  float qkc = 0.f;
  if (w == 1) {
    float t0 = kv0 * qv0;
#pragma unroll
    for (int d2 = 32; d2 >= 1; d2 >>= 1) t0 += __shfl_xor(t0, d2, 64);
    qkc = t0;
  }

  float alf = 1.f, als = 1.f;          // actual = alpha * repr
  float Nf = 0.f, Ns = 0.f, Cc = 0.f;  // actual-scale norm trackers
  float fdp = 1.f, sdp = 1.f;          // fd/sd of previous step (for chain)
  float fgp = 0.f, sgp = 0.f;          // gates of previous step
  float ofp = 0.f, osp = 0.f;          // deferred output dots (repr)
  float ef = 0.f, es = 0.f, gf = 0.f, gs = 0.f;

  for (int t = 0; t < 1024; ++t) {
    const int t1 = (t + 1) & 1023;
    const int t2 = (t + 2) & 1023;

    // ---- raw barrier: LDS-visibility only ----
    if (t > 0) {
      asm volatile("s_waitcnt lgkmcnt(0)" ::: "memory");
      __builtin_amdgcn_s_barrier();
    }

    // ---- prefetch ----
    const float kvB = kb[t2 * 64 + lane];
    const float qvB = qb[t2 * 64 + lane];
    const float vn  = vb[t1 * 64 + lane];
    const float4 scn = *(const float4*)&sb[(size_t)t1 * 8];
    const float sgn = sb[(size_t)t1 * 8 + 4];

    // ---- read partials + finish previous step's cap chain ----
    if (t > 0) {
      const int pr = (t - 1) & 1;
      float2 e0 = pE[pr][0][lane], e1 = pE[pr][1][lane];
      float2 e2 = pE[pr][2][lane], e3 = pE[pr][3][lane];
      float2 e4 = pE[pr][4][lane], e5 = pE[pr][5][lane];
      float2 e6 = pE[pr][6][lane], e7 = pE[pr][7][lane];
      float2 g0 = pG[pr][0][lane], g1 = pG[pr][1][lane];
      float2 g2 = pG[pr][2][lane], g3 = pG[pr][3][lane];
      float2 g4 = pG[pr][4][lane], g5 = pG[pr][5][lane];
      float2 g6 = pG[pr][6][lane], g7 = pG[pr][7][lane];
      ef = ((e0.x + e1.x) + (e2.x + e3.x)) + ((e4.x + e5.x) + (e6.x + e7.x));
      es = ((e0.y + e1.y) + (e2.y + e3.y)) + ((e4.y + e5.y) + (e6.y + e7.y));
      gf = ((g0.x + g1.x) + (g2.x + g3.x)) + ((g4.x + g5.x) + (g6.x + g7.x));
      gs = ((g0.y + g1.y) + (g2.y + g3.y)) + ((g4.y + g5.y) + (g6.y + g7.y));
      const float4 xv = xb[pr];
      const float Nfd = fmaf(fdp * fdp, Nf, xv.x);
      const float Nsd = fmaf(sdp * sdp, Ns, xv.y);
      const float Cd  = fmaf(fdp * sdp, Cc, xv.z);
      const float NTf = Nfd + 2.f * rf * Cd + rf2 * Nsd;
      const float NTs = Nsd + 2.f * rf * Cd + rf2 * Nfd;
      const float CT  = (1.f + rf2) * Cd + rf * (Nfd + Nsd);
      const bool capf = NTf > 4096.f;
      const bool caps = NTs > 4096.f;
      const float scf = capf ? 64.f * rsqrtf(NTf) : 1.f;
      const float scs = caps ? 64.f * rsqrtf(NTs) : 1.f;
      Nf = capf ? 4096.f : NTf;
      Ns = caps ? 4096.f : NTs;
      Cc = scf * scs * CT;
      alf *= scf; als *= scs;
      // deferred output for step t-1 (actual scale now known)
      if (w == 1)
        ob[(size_t)(t - 1) * 1024 + lane] = fgp * alf * ofp + sgp * als * osp;
    }

    const float bt = sc.x, fdt = sc.y, sdt = sc.z, fgt = sc.w, sgt = sg4;

    // ---- head: decayed scales, error, coefficients (repr) ----
    const float d_f = alf * fdt, d_s = als * sdt;
    const float EF = d_f * ef, ES = d_s * es;
    const float errf = vv - EF, errs = vv - ES;
    const float rdf = 1.f / d_f, rds = 1.f / d_s;
    const float beff = bt * errf * rdf;
    const float bess = bt * errs * rds;
    const float cfs = rf * d_s * rdf;
    const float csf = rf * d_f * rds;

    // ---- x-values for this step's cap (wave 0 only; spans the barrier) ----
    float x1 = 0.f, x2 = 0.f, x3 = 0.f;
    if (w == 0) {
      x1 = bt * errf * fmaf(bt, errf, 2.f * EF);
      x2 = bt * errs * fmaf(bt, errs, 2.f * ES);
      x3 = bt * (fmaf(bt, errf * errs, errs * EF) + errf * ES);
#pragma unroll
      for (int d2 = 32; d2 >= 1; d2 >>= 1) {
        x1 += __shfl_xor(x1, d2, 64);
        x2 += __shfl_xor(x2, d2, 64);
        x3 += __shfl_xor(x3, d2, 64);
      }
    }

    // ---- qk for t+1 + analytic output dots (wave 1 only) ----
    float qkn = 0.f, of_new = 0.f, os_new = 0.f;
    if (w == 1) {
      float t0 = kvA * qvA;
#pragma unroll
      for (int d2 = 32; d2 >= 1; d2 >>= 1) t0 += __shfl_xor(t0, d2, 64);
      qkn = t0;
      const float sfq = fmaf(qkc, beff, gf);
      const float svq = fmaf(qkc, bess, gs);
      of_new = fmaf(cfs, svq, sfq);   // q . Tf (repr)
      os_new = fmaf(csf, sfq, svq);
    }

    // ---- broadcast rows of k_{t+1}, q_{t+1} ----
    float kr1[8], qr1[8];
#pragma unroll
    for (int j = 0; j < 8; ++j) {
      kr1[j] = rdl_(kvA, w * 8 + j);
      qr1[j] = rdl_(qvA, w * 8 + j);
    }

    // ---- register pass: update + combine + fused t+1 dots ----
    float ef1 = 0.f, es1 = 0.f, gf1 = 0.f, gs1 = 0.f;
#pragma unroll
    for (int j = 0; j < 8; ++j) {
      float sfv = fmaf(kr[j], beff, Sf[j]);
      float svv = fmaf(kr[j], bess, Ss[j]);
      float tf = fmaf(cfs, svv, sfv);
      float ts = fmaf(csf, sfv, svv);
      ef1 = fmaf(kr1[j], tf, ef1);
      es1 = fmaf(kr1[j], ts, es1);
      gf1 = fmaf(qr1[j], tf, gf1);
      gs1 = fmaf(qr1[j], ts, gs1);
      Sf[j] = tf; Ss[j] = ts;
    }

    // ---- absorb decay into alpha; refold every 8 steps ----
    alf = d_f; als = d_s;
    if ((t & 7) == 7) {
#pragma unroll
      for (int j = 0; j < 8; ++j) { Sf[j] *= alf; Ss[j] *= als; }
      ef1 *= alf; gf1 *= alf; es1 *= als; gs1 *= als;
      of_new *= alf; os_new *= als;
      alf = 1.f; als = 1.f;
    }

    // ---- write partials + publish reduced x ----
    const int par = t & 1;
    pE[par][w][lane] = make_float2(ef1, es1);
    pG[par][w][lane] = make_float2(gf1, gs1);
    if (w == 0 && lane == 0) xb[par] = make_float4(x1, x2, x3, 0.f);

    // ---- rotate pipeline ----
#pragma unroll
    for (int j = 0; j < 8; ++j) kr[j] = kr1[j];
    kvA = kvB; qvA = qvB; vv = vn; sc = scn; sg4 = sgn; qkc = qkn;
    fdp = fdt; sdp = sdt; fgp = fgt; sgp = sgt;
    ofp = of_new; osp = os_new;
  }

  // ---- epilogue: finish cap for t=1023 and write its output ----
  asm volatile("s_waitcnt lgkmcnt(0)" ::: "memory");
  __builtin_amdgcn_s_barrier();
  if (w == 1) {
    const float4 xv = xb[1023 & 1];
    const float Nfd = fmaf(fdp * fdp, Nf, xv.x);
    const float Nsd = fmaf(sdp * sdp, Ns, xv.y);
    const float Cd  = fmaf(fdp * sdp, Cc, xv.z);
    const float NTf = Nfd + 2.f * rf * Cd + rf2 * Nsd;
    const float NTs = Nsd + 2.f * rf * Cd + rf2 * Nfd;
    const float scf = (NTf > 4096.f) ? 64.f * rsqrtf(NTf) : 1.f;
    const float scs = (NTs > 4096.f) ? 64.f * rsqrtf(NTs) : 1.f;
    alf *= scf; als *= scs;
    ob[(size_t)1023 * 1024 + lane] = fgp * alf * ofp + sgp * als * osp;
  }
}

// ---------------------------------------------------------------------------
// Gated RMSNorm: og = o * rsqrt(mean(o^2)+eps) * onorm_w * silu_g (g pre-silu'd)
// ---------------------------------------------------------------------------
__global__ __launch_bounds__(256) void rms_gate(
    const float* __restrict__ o, const float* __restrict__ gsil,
    const float* __restrict__ onw, float* __restrict__ og)
{
  int gi = blockIdx.x * 4 + (threadIdx.x >> 6);
  int lane = threadIdx.x & 63;
  size_t idx = (size_t)gi * 64 + lane;
  float x = o[idx];
  float ss = x * x;
#pragma unroll
  for (int d2 = 32; d2 >= 1; d2 >>= 1) ss += __shfl_xor(ss, d2, 64);
  float r = rsqrtf(ss * (1.f / 64.f) + 1e-5f);
  og[idx] = x * r * onw[lane] * gsil[idx];
}

// ---------------------------------------------------------------------------
// Host launcher
// ---------------------------------------------------------------------------
extern "C" void kernel_launch(void* const* d_in, const int* in_sizes, int n_in,
                              void* d_out, int out_size, void* d_ws, size_t ws_size,
                              hipStream_t stream)
{
  const float* hs  = (const float*)d_in[0];
  const float* Wq  = (const float*)d_in[1];
  const float* bq  = (const float*)d_in[2];
  const float* Wk  = (const float*)d_in[3];
  const float* bk  = (const float*)d_in[4];
  const float* Wv  = (const float*)d_in[5];
  const float* bv  = (const float*)d_in[6];
  const float* Wb  = (const float*)d_in[7];
  const float* bb  = (const float*)d_in[8];
  const float* Wfd = (const float*)d_in[9];
  const float* bfd = (const float*)d_in[10];
  const float* fdb = (const float*)d_in[11];
  const float* Wsd = (const float*)d_in[12];
  const float* bsd = (const float*)d_in[13];
  const float* sdb = (const float*)d_in[14];
  const float* Wfg = (const float*)d_in[15];
  const float* bfg = (const float*)d_in[16];
  const float* Wsg = (const float*)d_in[17];
  const float* bsg = (const float*)d_in[18];
  const float* Wg  = (const float*)d_in[19];
  const float* bg  = (const float*)d_in[20];
  const float* onw = (const float*)d_in[21];
  const float* Wo  = (const float*)d_in[22];
  const float* bo  = (const float*)d_in[23];
  const float* rfx = (const float*)d_in[24];

  float* ws = (float*)d_ws;
  const size_t TWO_M = (size_t)1 << 21;  // 2M floats = B*H*L*64
  float* q_ws  = ws;                     // q and k contiguous for prenorm
  float* k_ws  = ws + TWO_M;
  float* v_ws  = ws + 2 * TWO_M;
  float* g_ws  = ws + 3 * TWO_M;
  float* o_ws  = ws + 4 * TWO_M;
  float* scl_ws = ws + 5 * TWO_M;        // 32*1024*8 floats packed scalars
  float* og_ws = q_ws;  // reuse q buffer (scan has consumed it)

  // 1) big projections: q,k,v (silu + scatter), g (silu, linear)
  GemmBatch gb1;
  gb1.s[0].W = Wq; gb1.s[0].bias = bq; gb1.s[0].out = q_ws; gb1.s[0].mode = 2;
  gb1.s[1].W = Wk; gb1.s[1].bias = bk; gb1.s[1].out = k_ws; gb1.s[1].mode = 2;
  gb1.s[2].W = Wv; gb1.s[2].bias = bv; gb1.s[2].out = v_ws; gb1.s[2].mode = 2;
  gb1.s[3].W = Wg; gb1.s[3].bias = bg; gb1.s[3].out = g_ws; gb1.s[3].mode = 1;
  gemm_act<<<dim3(32, 16, 4), 256, 0, stream>>>(hs, gb1, 2048, 1024, 1024);

  // 2) per-head scalar projections (LDS-tiled, packed output)
  scalar_proj<<<256, 256, 0, stream>>>(hs, Wb, bb, Wfd, bfd, fdb, Wsd, bsd, sdb,
                                       Wfg, bfg, Wsg, bsg, scl_ws);

  // 3) pre-normalize q,k (contiguous 4M floats = 65536 rows of 64)
  prenorm<<<16384, 256, 0, stream>>>(q_ws);

  // 4) sequential dual-state delta-rule scan: 8 waves, deferred-cap schedule
  scan_kernel<<<32, 512, 0, stream>>>(q_ws, k_ws, v_ws, scl_ws, rfx, o_ws);

  // 5) gated RMSNorm
  rms_gate<<<8192, 256, 0, stream>>>(o_ws, g_ws, onw, og_ws);

  // 6) output projection -> d_out
  GemmBatch gb2;
  gb2.s[0].W = Wo; gb2.s[0].bias = bo; gb2.s[0].out = (float*)d_out; gb2.s[0].mode = 0;
  gb2.s[1] = gb2.s[0]; gb2.s[2] = gb2.s[0]; gb2.s[3] = gb2.s[0];
  gemm_act<<<dim3(32, 16, 1), 256, 0, stream>>>(og_ws, gb2, 2048, 1024, 1024);
}

// Round 14
// 1437.180 us; speedup vs baseline: 1.1835x; 1.0012x over previous
//
#include <hip/hip_runtime.h>

// ---------------------------------------------------------------------------
// Problem constants: B=2, L=1024, D=1024, H=16, DK=DV=64
// ---------------------------------------------------------------------------

struct GemmSlot { const float* W; const float* bias; float* out; int mode; };
struct GemmBatch { GemmSlot s[4]; };

__device__ __forceinline__ float silu_(float x) {
  return x / (1.f + __expf(-x));
}
__device__ __forceinline__ float sigm_(float x) {
  return 1.f / (1.f + __expf(-x));
}
__device__ __forceinline__ float rdl_(float v, int l) {
  return __int_as_float(__builtin_amdgcn_readlane(__float_as_int(v), l));
}

// ---------------------------------------------------------------------------
// fp32 GEMM v2: 128x64 tile, 8x4 micro (91% FMA density), software-pipelined
// staging (next tile's global loads issued right after the store barrier,
// consumed next iteration -> HBM/L2 latency hides under the 16-kk compute).
// mode 0: raw, linear store; mode 1: silu, linear; mode 2: silu, scatter BHLd
// ---------------------------------------------------------------------------
#define GTM 128
#define GTN 64
#define GTK 16

__global__ __launch_bounds__(256) void gemm_act(
    const float* __restrict__ A, GemmBatch gb, int M, int N, int K)
{
  const GemmSlot sl = gb.s[blockIdx.z];
  const float* __restrict__ W = sl.W;

  __shared__ float As[GTK][GTM + 4];  // transposed A tile, padded
  __shared__ float Ws[GTK][GTN];

  const int tid = threadIdx.x;
  const int bm = blockIdx.x * GTM;
  const int bn = blockIdx.y * GTN;
  const int tm = (tid >> 4) << 3;    // 0..120
  const int tn = (tid & 15) << 2;    // 0..60
  const int la_r0 = tid >> 2;        // 0..63   (A float4 #0: rows 0..63)
  const int la_c = (tid & 3) << 2;   // 0,4,8,12
  const int lw_r = tid >> 4;         // 0..15
  const int lw_c = (tid & 15) << 2;  // 0..60

  float acc[8][4];
#pragma unroll
  for (int i = 0; i < 8; ++i)
#pragma unroll
    for (int j = 0; j < 4; ++j) acc[i][j] = 0.f;

  const int ntiles = K / GTK;
  // preload tile 0
  float4 av0 = *(const float4*)&A[(size_t)(bm + la_r0) * K + la_c];
  float4 av1 = *(const float4*)&A[(size_t)(bm + 64 + la_r0) * K + la_c];
  float4 wv  = *(const float4*)&W[(size_t)lw_r * N + bn + lw_c];

  for (int kt = 0; kt < ntiles; ++kt) {
    __syncthreads();   // previous compute done reading LDS
    As[la_c + 0][la_r0] = av0.x;
    As[la_c + 1][la_r0] = av0.y;
    As[la_c + 2][la_r0] = av0.z;
    As[la_c + 3][la_r0] = av0.w;
    As[la_c + 0][64 + la_r0] = av1.x;
    As[la_c + 1][64 + la_r0] = av1.y;
    As[la_c + 2][64 + la_r0] = av1.z;
    As[la_c + 3][64 + la_r0] = av1.w;
    *(float4*)&Ws[lw_r][lw_c] = wv;
    __syncthreads();   // tile visible

    // issue next tile's loads: latency hides under the compute below
    if (kt + 1 < ntiles) {
      const int kb = (kt + 1) * GTK;
      av0 = *(const float4*)&A[(size_t)(bm + la_r0) * K + kb + la_c];
      av1 = *(const float4*)&A[(size_t)(bm + 64 + la_r0) * K + kb + la_c];
      wv  = *(const float4*)&W[(size_t)(kb + lw_r) * N + bn + lw_c];
    }

#pragma unroll
    for (int kk = 0; kk < GTK; ++kk) {
      float4 a0 = *(const float4*)&As[kk][tm];
      float4 a1 = *(const float4*)&As[kk][tm + 4];
      float4 b = *(const float4*)&Ws[kk][tn];
      acc[0][0] = fmaf(a0.x, b.x, acc[0][0]);
      acc[0][1] = fmaf(a0.x, b.y, acc[0][1]);
      acc[0][2] = fmaf(a0.x, b.z, acc[0][2]);
      acc[0][3] = fmaf(a0.x, b.w, acc[0][3]);
      acc[1][0] = fmaf(a0.y, b.x, acc[1][0]);
      acc[1][1] = fmaf(a0.y, b.y, acc[1][1]);
      acc[1][2] = fmaf(a0.y, b.z, acc[1][2]);
      acc[1][3] = fmaf(a0.y, b.w, acc[1][3]);
      acc[2][0] = fmaf(a0.z, b.x, acc[2][0]);
      acc[2][1] = fmaf(a0.z, b.y, acc[2][1]);
      acc[2][2] = fmaf(a0.z, b.z, acc[2][2]);
      acc[2][3] = fmaf(a0.z, b.w, acc[2][3]);
      acc[3][0] = fmaf(a0.w, b.x, acc[3][0]);
      acc[3][1] = fmaf(a0.w, b.y, acc[3][1]);
      acc[3][2] = fmaf(a0.w, b.z, acc[3][2]);
      acc[3][3] = fmaf(a0.w, b.w, acc[3][3]);
      acc[4][0] = fmaf(a1.x, b.x, acc[4][0]);
      acc[4][1] = fmaf(a1.x, b.y, acc[4][1]);
      acc[4][2] = fmaf(a1.x, b.z, acc[4][2]);
      acc[4][3] = fmaf(a1.x, b.w, acc[4][3]);
      acc[5][0] = fmaf(a1.y, b.x, acc[5][0]);
      acc[5][1] = fmaf(a1.y, b.y, acc[5][1]);
      acc[5][2] = fmaf(a1.y, b.z, acc[5][2]);
      acc[5][3] = fmaf(a1.y, b.w, acc[5][3]);
      acc[6][0] = fmaf(a1.z, b.x, acc[6][0]);
      acc[6][1] = fmaf(a1.z, b.y, acc[6][1]);
      acc[6][2] = fmaf(a1.z, b.z, acc[6][2]);
      acc[6][3] = fmaf(a1.z, b.w, acc[6][3]);
      acc[7][0] = fmaf(a1.w, b.x, acc[7][0]);
      acc[7][1] = fmaf(a1.w, b.y, acc[7][1]);
      acc[7][2] = fmaf(a1.w, b.z, acc[7][2]);
      acc[7][3] = fmaf(a1.w, b.w, acc[7][3]);
    }
  }

  const float* bias = sl.bias;
  float* out = sl.out;
  const int mode = sl.mode;
#pragma unroll
  for (int i = 0; i < 8; ++i) {
#pragma unroll
    for (int j = 0; j < 4; ++j) {
      int m = bm + tm + i, n = bn + tn + j;
      float c = acc[i][j] + bias[n];
      if (mode >= 1) c = silu_(c);
      if (mode == 2) {
        int h = n >> 6, d = n & 63;
        int b = m >> 10, l = m & 1023;
        out[(((size_t)(b * 16 + h)) * 1024 + l) * 64 + d] = c;
      } else {
        out[(size_t)m * N + n] = c;
      }
    }
  }
}

// ---------------------------------------------------------------------------
// Scalar projections: LDS-tiled (8 hs rows/block), packed scl[bh][t][8]
// ---------------------------------------------------------------------------
__global__ __launch_bounds__(256) void scalar_proj(
    const float* __restrict__ hs,
    const float* __restrict__ Wb,  const float* __restrict__ bb,
    const float* __restrict__ Wfd, const float* __restrict__ bfd, const float* __restrict__ fdb,
    const float* __restrict__ Wsd, const float* __restrict__ bsd, const float* __restrict__ sdb,
    const float* __restrict__ Wfg, const float* __restrict__ bfg,
    const float* __restrict__ Wsg, const float* __restrict__ bsg,
    float* __restrict__ scl)
{
  __shared__ float hl[8][1028];
  const int tid = threadIdx.x;
  const int m0 = blockIdx.x * 8;

#pragma unroll
  for (int i = 0; i < 8; ++i) {
    int f = tid + 256 * i;        // 0..2047 float4s
    int r = f >> 8;
    int c4 = f & 255;
    float4 v = *(const float4*)&hs[(size_t)(m0 + r) * 1024 + c4 * 4];
    *(float4*)&hl[r][c4 * 4] = v;
  }
  __syncthreads();

  for (int c = 0; c < 3; ++c) {
    int o = tid + 256 * c;
    if (o >= 640) break;
    int ml = o / 80;
    int cc = o - ml * 80;
    int type = cc >> 4;
    int h = cc & 15;
    const float* W; const float* bias; float extra = 0.f;
    switch (type) {
      case 0:  W = Wb;  bias = bb;  break;
      case 1:  W = Wfd; bias = bfd; extra = fdb[h]; break;
      case 2:  W = Wsd; bias = bsd; extra = sdb[h]; break;
      case 3:  W = Wfg; bias = bfg; break;
      default: W = Wsg; bias = bsg; break;
    }
    float s = 0.f;
    for (int k = 0; k < 1024; k += 4) {
      float4 hv = *(const float4*)&hl[ml][k];
      s = fmaf(hv.x, W[(k + 0) * 16 + h], s);
      s = fmaf(hv.y, W[(k + 1) * 16 + h], s);
      s = fmaf(hv.z, W[(k + 2) * 16 + h], s);
      s = fmaf(hv.w, W[(k + 3) * 16 + h], s);
    }
    s += bias[h] + extra;
    int m = m0 + ml;
    int b = m >> 10, l = m & 1023;
    scl[((size_t)((b * 16 + h) * 1024 + l)) * 8 + type] = sigm_(s);
  }
}

// ---------------------------------------------------------------------------
// Pre-normalize q and k in place: x *= rsqrt(sum_64(x^2)+1e-6).
// ---------------------------------------------------------------------------
__global__ __launch_bounds__(256) void prenorm(float* __restrict__ p)
{
  int wid = blockIdx.x * 4 + (threadIdx.x >> 6);
  int lane = threadIdx.x & 63;
  size_t idx = (size_t)wid * 64 + lane;
  float x = p[idx];
  float ss = x * x;
#pragma unroll
  for (int d2 = 32; d2 >= 1; d2 >>= 1) ss += __shfl_xor(ss, d2, 64);
  p[idx] = x * rsqrtf(ss + 1e-6f);
}

// ---------------------------------------------------------------------------
// Sequential scan, v13 (unchanged from r13, 1094us, passed): 8 waves x 8
// rows, one raw barrier/step, deferred cap (x-shfl spans the barrier),
// wave-specialized reduces, refold every 8 steps.
// ---------------------------------------------------------------------------
__global__ __launch_bounds__(512) void scan_kernel(
    const float* __restrict__ qg, const float* __restrict__ kg, const float* __restrict__ vg,
    const float* __restrict__ scl, const float* __restrict__ rfx, float* __restrict__ og)
{
  const int bh = blockIdx.x;     // 0..31
  const int tid = threadIdx.x;
  const int lane = tid & 63;     // column index
  const int w = tid >> 6;        // wave id 0..7: rows [8w, 8w+8)
  const float rf = rfx[0];
  const float rf2 = rf * rf;

  __shared__ float2 pE[2][8][64];  // {ef,es} partials, double-buffered
  __shared__ float2 pG[2][8][64];  // {gf,gs} partials
  __shared__ float4 xb[2];         // reduced x1,x2,x3 from wave 0

  float Sf[8], Ss[8];
#pragma unroll
  for (int j = 0; j < 8; ++j) { Sf[j] = 0.f; Ss[j] = 0.f; }

  const float* kb = kg + (size_t)bh * 65536;
  const float* qb = qg + (size_t)bh * 65536;
  const float* vb = vg + (size_t)bh * 65536;
  const float* sb = scl + (size_t)bh * 8192;
  const int b = bh >> 4, h = bh & 15;
  float* ob = og + (size_t)b * (1024 * 1024) + h * 64;  // + t*1024 + lane

  // ---- prologue ----
  float kv0 = kb[lane], qv0 = qb[lane];
  float kvA = kb[64 + lane], qvA = qb[64 + lane];   // t=1 per-lane
  float vv = vb[lane];
  float4 sc = *(const float4*)&sb[0];
  float sg4 = sb[4];

  float kr[8];
#pragma unroll
  for (int j = 0; j < 8; ++j) kr[j] = rdl_(kv0, w * 8 + j);

  float qkc = 0.f;
  if (w == 1) {
    float t0 = kv0 * qv0;
#pragma unroll
    for (int d2 = 32; d2 >= 1; d2 >>= 1) t0 += __shfl_xor(t0, d2, 64);
    qkc = t0;
  }

  float alf = 1.f, als = 1.f;          // actual = alpha * repr
  float Nf = 0.f, Ns = 0.f, Cc = 0.f;  // actual-scale norm trackers
  float fdp = 1.f, sdp = 1.f;          // fd/sd of previous step (for chain)
  float fgp = 0.f, sgp = 0.f;          // gates of previous step
  float ofp = 0.f, osp = 0.f;          // deferred output dots (repr)
  float ef = 0.f, es = 0.f, gf = 0.f, gs = 0.f;

  for (int t = 0; t < 1024; ++t) {
    const int t1 = (t + 1) & 1023;
    const int t2 = (t + 2) & 1023;

    // ---- raw barrier: LDS-visibility only ----
    if (t > 0) {
      asm volatile("s_waitcnt lgkmcnt(0)" ::: "memory");
      __builtin_amdgcn_s_barrier();
    }

    // ---- prefetch ----
    const float kvB = kb[t2 * 64 + lane];
    const float qvB = qb[t2 * 64 + lane];
    const float vn  = vb[t1 * 64 + lane];
    const float4 scn = *(const float4*)&sb[(size_t)t1 * 8];
    const float sgn = sb[(size_t)t1 * 8 + 4];

    // ---- read partials + finish previous step's cap chain ----
    if (t > 0) {
      const int pr = (t - 1) & 1;
      float2 e0 = pE[pr][0][lane], e1 = pE[pr][1][lane];
      float2 e2 = pE[pr][2][lane], e3 = pE[pr][3][lane];
      float2 e4 = pE[pr][4][lane], e5 = pE[pr][5][lane];
      float2 e6 = pE[pr][6][lane], e7 = pE[pr][7][lane];
      float2 g0 = pG[pr][0][lane], g1 = pG[pr][1][lane];
      float2 g2 = pG[pr][2][lane], g3 = pG[pr][3][lane];
      float2 g4 = pG[pr][4][lane], g5 = pG[pr][5][lane];
      float2 g6 = pG[pr][6][lane], g7 = pG[pr][7][lane];
      ef = ((e0.x + e1.x) + (e2.x + e3.x)) + ((e4.x + e5.x) + (e6.x + e7.x));
      es = ((e0.y + e1.y) + (e2.y + e3.y)) + ((e4.y + e5.y) + (e6.y + e7.y));
      gf = ((g0.x + g1.x) + (g2.x + g3.x)) + ((g4.x + g5.x) + (g6.x + g7.x));
      gs = ((g0.y + g1.y) + (g2.y + g3.y)) + ((g4.y + g5.y) + (g6.y + g7.y));
      const float4 xv = xb[pr];
      const float Nfd = fmaf(fdp * fdp, Nf, xv.x);
      const float Nsd = fmaf(sdp * sdp, Ns, xv.y);
      const float Cd  = fmaf(fdp * sdp, Cc, xv.z);
      const float NTf = Nfd + 2.f * rf * Cd + rf2 * Nsd;
      const float NTs = Nsd + 2.f * rf * Cd + rf2 * Nfd;
      const float CT  = (1.f + rf2) * Cd + rf * (Nfd + Nsd);
      const bool capf = NTf > 4096.f;
      const bool caps = NTs > 4096.f;
      const float scf = capf ? 64.f * rsqrtf(NTf) : 1.f;
      const float scs = caps ? 64.f * rsqrtf(NTs) : 1.f;
      Nf = capf ? 4096.f : NTf;
      Ns = caps ? 4096.f : NTs;
      Cc = scf * scs * CT;
      alf *= scf; als *= scs;
      // deferred output for step t-1 (actual scale now known)
      if (w == 1)
        ob[(size_t)(t - 1) * 1024 + lane] = fgp * alf * ofp + sgp * als * osp;
    }

    const float bt = sc.x, fdt = sc.y, sdt = sc.z, fgt = sc.w, sgt = sg4;

    // ---- head: decayed scales, error, coefficients (repr) ----
    const float d_f = alf * fdt, d_s = als * sdt;
    const float EF = d_f * ef, ES = d_s * es;
    const float errf = vv - EF, errs = vv - ES;
    const float rdf = 1.f / d_f, rds = 1.f / d_s;
    const float beff = bt * errf * rdf;
    const float bess = bt * errs * rds;
    const float cfs = rf * d_s * rdf;
    const float csf = rf * d_f * rds;

    // ---- x-values for this step's cap (wave 0 only; spans the barrier) ----
    float x1 = 0.f, x2 = 0.f, x3 = 0.f;
    if (w == 0) {
      x1 = bt * errf * fmaf(bt, errf, 2.f * EF);
      x2 = bt * errs * fmaf(bt, errs, 2.f * ES);
      x3 = bt * (fmaf(bt, errf * errs, errs * EF) + errf * ES);
#pragma unroll
      for (int d2 = 32; d2 >= 1; d2 >>= 1) {
        x1 += __shfl_xor(x1, d2, 64);
        x2 += __shfl_xor(x2, d2, 64);
        x3 += __shfl_xor(x3, d2, 64);
      }
    }

    // ---- qk for t+1 + analytic output dots (wave 1 only) ----
    float qkn = 0.f, of_new = 0.f, os_new = 0.f;
    if (w == 1) {
      float t0 = kvA * qvA;
#pragma unroll
      for (int d2 = 32; d2 >= 1; d2 >>= 1) t0 += __shfl_xor(t0, d2, 64);
      qkn = t0;
      const float sfq = fmaf(qkc, beff, gf);
      const float svq = fmaf(qkc, bess, gs);
      of_new = fmaf(cfs, svq, sfq);   // q . Tf (repr)
      os_new = fmaf(csf, sfq, svq);
    }

    // ---- broadcast rows of k_{t+1}, q_{t+1} ----
    float kr1[8], qr1[8];
#pragma unroll
    for (int j = 0; j < 8; ++j) {
      kr1[j] = rdl_(kvA, w * 8 + j);
      qr1[j] = rdl_(qvA, w * 8 + j);
    }

    // ---- register pass: update + combine + fused t+1 dots ----
    float ef1 = 0.f, es1 = 0.f, gf1 = 0.f, gs1 = 0.f;
#pragma unroll
    for (int j = 0; j < 8; ++j) {
      float sfv = fmaf(kr[j], beff, Sf[j]);
      float svv = fmaf(kr[j], bess, Ss[j]);
      float tf = fmaf(cfs, svv, sfv);
      float ts = fmaf(csf, sfv, svv);
      ef1 = fmaf(kr1[j], tf, ef1);
      es1 = fmaf(kr1[j], ts, es1);
      gf1 = fmaf(qr1[j], tf, gf1);
      gs1 = fmaf(qr1[j], ts, gs1);
      Sf[j] = tf; Ss[j] = ts;
    }

    // ---- absorb decay into alpha; refold every 8 steps ----
    alf = d_f; als = d_s;
    if ((t & 7) == 7) {
#pragma unroll
      for (int j = 0; j < 8; ++j) { Sf[j] *= alf; Ss[j] *= als; }
      ef1 *= alf; gf1 *= alf; es1 *= als; gs1 *= als;
      of_new *= alf; os_new *= als;
      alf = 1.f; als = 1.f;
    }

    // ---- write partials + publish reduced x ----
    const int par = t & 1;
    pE[par][w][lane] = make_float2(ef1, es1);
    pG[par][w][lane] = make_float2(gf1, gs1);
    if (w == 0 && lane == 0) xb[par] = make_float4(x1, x2, x3, 0.f);

    // ---- rotate pipeline ----
#pragma unroll
    for (int j = 0; j < 8; ++j) kr[j] = kr1[j];
    kvA = kvB; qvA = qvB; vv = vn; sc = scn; sg4 = sgn; qkc = qkn;
    fdp = fdt; sdp = sdt; fgp = fgt; sgp = sgt;
    ofp = of_new; osp = os_new;
  }

  // ---- epilogue: finish cap for t=1023 and write its output ----
  asm volatile("s_waitcnt lgkmcnt(0)" ::: "memory");
  __builtin_amdgcn_s_barrier();
  if (w == 1) {
    const float4 xv = xb[1023 & 1];
    const float Nfd = fmaf(fdp * fdp, Nf, xv.x);
    const float Nsd = fmaf(sdp * sdp, Ns, xv.y);
    const float Cd  = fmaf(fdp * sdp, Cc, xv.z);
    const float NTf = Nfd + 2.f * rf * Cd + rf2 * Nsd;
    const float NTs = Nsd + 2.f * rf * Cd + rf2 * Nfd;
    const float scf = (NTf > 4096.f) ? 64.f * rsqrtf(NTf) : 1.f;
    const float scs = (NTs > 4096.f) ? 64.f * rsqrtf(NTs) : 1.f;
    alf *= scf; als *= scs;
    ob[(size_t)1023 * 1024 + lane] = fgp * alf * ofp + sgp * als * osp;
  }
}

// ---------------------------------------------------------------------------
// Gated RMSNorm: og = o * rsqrt(mean(o^2)+eps) * onorm_w * silu_g (g pre-silu'd)
// ---------------------------------------------------------------------------
__global__ __launch_bounds__(256) void rms_gate(
    const float* __restrict__ o, const float* __restrict__ gsil,
    const float* __restrict__ onw, float* __restrict__ og)
{
  int gi = blockIdx.x * 4 + (threadIdx.x >> 6);
  int lane = threadIdx.x & 63;
  size_t idx = (size_t)gi * 64 + lane;
  float x = o[idx];
  float ss = x * x;
#pragma unroll
  for (int d2 = 32; d2 >= 1; d2 >>= 1) ss += __shfl_xor(ss, d2, 64);
  float r = rsqrtf(ss * (1.f / 64.f) + 1e-5f);
  og[idx] = x * r * onw[lane] * gsil[idx];
}

// ---------------------------------------------------------------------------
// Host launcher
// ---------------------------------------------------------------------------
extern "C" void kernel_launch(void* const* d_in, const int* in_sizes, int n_in,
                              void* d_out, int out_size, void* d_ws, size_t ws_size,
                              hipStream_t stream)
{
  const float* hs  = (const float*)d_in[0];
  const float* Wq  = (const float*)d_in[1];
  const float* bq  = (const float*)d_in[2];
  const float* Wk  = (const float*)d_in[3];
  const float* bk  = (const float*)d_in[4];
  const float* Wv  = (const float*)d_in[5];
  const float* bv  = (const float*)d_in[6];
  const float* Wb  = (const float*)d_in[7];
  const float* bb  = (const float*)d_in[8];
  const float* Wfd = (const float*)d_in[9];
  const float* bfd = (const float*)d_in[10];
  const float* fdb = (const float*)d_in[11];
  const float* Wsd = (const float*)d_in[12];
  const float* bsd = (const float*)d_in[13];
  const float* sdb = (const float*)d_in[14];
  const float* Wfg = (const float*)d_in[15];
  const float* bfg = (const float*)d_in[16];
  const float* Wsg = (const float*)d_in[17];
  const float* bsg = (const float*)d_in[18];
  const float* Wg  = (const float*)d_in[19];
  const float* bg  = (const float*)d_in[20];
  const float* onw = (const float*)d_in[21];
  const float* Wo  = (const float*)d_in[22];
  const float* bo  = (const float*)d_in[23];
  const float* rfx = (const float*)d_in[24];

  float* ws = (float*)d_ws;
  const size_t TWO_M = (size_t)1 << 21;  // 2M floats = B*H*L*64
  float* q_ws  = ws;                     // q and k contiguous for prenorm
  float* k_ws  = ws + TWO_M;
  float* v_ws  = ws + 2 * TWO_M;
  float* g_ws  = ws + 3 * TWO_M;
  float* o_ws  = ws + 4 * TWO_M;
  float* scl_ws = ws + 5 * TWO_M;        // 32*1024*8 floats packed scalars
  float* og_ws = q_ws;  // reuse q buffer (scan has consumed it)

  // 1) big projections: q,k,v (silu + scatter), g (silu, linear)
  GemmBatch gb1;
  gb1.s[0].W = Wq; gb1.s[0].bias = bq; gb1.s[0].out = q_ws; gb1.s[0].mode = 2;
  gb1.s[1].W = Wk; gb1.s[1].bias = bk; gb1.s[1].out = k_ws; gb1.s[1].mode = 2;
  gb1.s[2].W = Wv; gb1.s[2].bias = bv; gb1.s[2].out = v_ws; gb1.s[2].mode = 2;
  gb1.s[3].W = Wg; gb1.s[3].bias = bg; gb1.s[3].out = g_ws; gb1.s[3].mode = 1;
  gemm_act<<<dim3(16, 16, 4), 256, 0, stream>>>(hs, gb1, 2048, 1024, 1024);

  // 2) per-head scalar projections (LDS-tiled, packed output)
  scalar_proj<<<256, 256, 0, stream>>>(hs, Wb, bb, Wfd, bfd, fdb, Wsd, bsd, sdb,
                                       Wfg, bfg, Wsg, bsg, scl_ws);

  // 3) pre-normalize q,k (contiguous 4M floats = 65536 rows of 64)
  prenorm<<<16384, 256, 0, stream>>>(q_ws);

  // 4) sequential dual-state delta-rule scan (unchanged r13)
  scan_kernel<<<32, 512, 0, stream>>>(q_ws, k_ws, v_ws, scl_ws, rfx, o_ws);

  // 5) gated RMSNorm
  rms_gate<<<8192, 256, 0, stream>>>(o_ws, g_ws, onw, og_ws);

  // 6) output projection -> d_out
  GemmBatch gb2;
  gb2.s[0].W = Wo; gb2.s[0].bias = bo; gb2.s[0].out = (float*)d_out; gb2.s[0].mode = 0;
  gb2.s[1] = gb2.s[0]; gb2.s[2] = gb2.s[0]; gb2.s[3] = gb2.s[0];
  gemm_act<<<dim3(16, 16, 1), 256, 0, stream>>>(og_ws, gb2, 2048, 1024, 1024);
}

// Round 16
// 1391.137 us; speedup vs baseline: 1.2226x; 1.0331x over previous
//
#include <hip/hip_runtime.h>

// ---------------------------------------------------------------------------
// Problem constants: B=2, L=1024, D=1024, H=16, DK=DV=64
// ---------------------------------------------------------------------------

typedef unsigned short u16;
typedef u16  u16x4 __attribute__((ext_vector_type(4)));
typedef short bf16x8 __attribute__((ext_vector_type(8)));
typedef float f32x4 __attribute__((ext_vector_type(4)));

struct MSlot { const u16* Wh; const u16* Wl; const float* bias; float* out; int mode; };
struct MBatch { MSlot s[4]; };
struct WSplitSlot { const float* W; u16* Th; u16* Tl; };
struct WSplitBatch { WSplitSlot s[5]; };

__device__ __forceinline__ float silu_(float x) {
  return x / (1.f + __expf(-x));
}
__device__ __forceinline__ float sigm_(float x) {
  return 1.f / (1.f + __expf(-x));
}
__device__ __forceinline__ float rdl_(float v, int l) {
  return __int_as_float(__builtin_amdgcn_readlane(__float_as_int(v), l));
}
// round-to-nearest-even bf16 split: x ~= hi + lo (each bf16), err ~ x*2^-17
__device__ __forceinline__ void split2_(float x, u16& h, u16& l) {
  unsigned u = __float_as_uint(x);
  unsigned r = (u + 0x7FFFu + ((u >> 16) & 1u)) >> 16;
  h = (u16)r;
  float lo = x - __uint_as_float(r << 16);
  unsigned u2 = __float_as_uint(lo);
  unsigned r2 = (u2 + 0x7FFFu + ((u2 >> 16) & 1u)) >> 16;
  l = (u16)r2;
}

// ---------------------------------------------------------------------------
// split_mk: X[n] f32 -> H[n], L[n] bf16 (hi/lo), float4-vectorized.
// ---------------------------------------------------------------------------
__global__ __launch_bounds__(256) void split_mk(
    const float* __restrict__ X, u16* __restrict__ H, u16* __restrict__ L, int n4)
{
  int i = blockIdx.x * 256 + threadIdx.x;
  if (i >= n4) return;
  float4 x = ((const float4*)X)[i];
  u16 h0, h1, h2, h3, l0, l1, l2, l3;
  split2_(x.x, h0, l0);
  split2_(x.y, h1, l1);
  split2_(x.z, h2, l2);
  split2_(x.w, h3, l3);
  u16x4 h, l;
  h.x = h0; h.y = h1; h.z = h2; h.w = h3;
  l.x = l0; l.y = l1; l.z = l2; l.w = l3;
  ((u16x4*)H)[i] = h;
  ((u16x4*)L)[i] = l;
}

// ---------------------------------------------------------------------------
// splitT: W[1024][1024] f32 -> Th[N][K], Tl[N][K] bf16 (transposed + split).
// 32x32 LDS tile transpose; 5 matrices via blockIdx.z.
// ---------------------------------------------------------------------------
__global__ __launch_bounds__(256) void splitT(WSplitBatch wb)
{
  const WSplitSlot sl = wb.s[blockIdx.z];
  __shared__ float tl[32][33];
  const int tid = threadIdx.x;
  const int k0 = blockIdx.x * 32, n0 = blockIdx.y * 32;
  const int c = tid & 31, r8 = tid >> 5;  // c: 0..31, r8: 0..7
#pragma unroll
  for (int j = 0; j < 4; ++j) {
    int r = r8 + 8 * j;
    tl[r][c] = sl.W[(size_t)(k0 + r) * 1024 + n0 + c];
  }
  __syncthreads();
#pragma unroll
  for (int j = 0; j < 4; ++j) {
    int nr = r8 + 8 * j;
    float x = tl[c][nr];
    u16 h, l;
    split2_(x, h, l);
    sl.Th[(size_t)(n0 + nr) * 1024 + k0 + c] = h;
    sl.Tl[(size_t)(n0 + nr) * 1024 + k0 + c] = l;
  }
}

// ---------------------------------------------------------------------------
// Split-bf16 MFMA GEMM: C = act(A @ W + bias), A[M][K] via (Ah+Al), W via
// pre-transposed (Wh+Wl)[N][K]. 3-product split (hh + hl + lh), fp32 acc.
// LDS-free: each lane loads its 16B fragment directly (L2/L3-resident data;
// lanes l, l+16, l+32, l+48 share one 64B line -> fully-utilized lines).
// Fragment layouts (guide §3): A row=lane&15, k=(lane>>4)*8+i;
// B col=lane&15, same k; D col=lane&15, row=(lane>>4)*4+reg [m89-verified].
// Block 256 thr = 4 waves; wave w: rows [bm+32w, bm+32w+32) (2 row-frags),
// all 4 col-frags; acc[2][4] f32x4. 24 MFMA + 12 loads per K-step.
// mode 0: raw linear; 1: silu linear; 2: silu scatter [B,H,L,64].
// ---------------------------------------------------------------------------
__global__ __launch_bounds__(256) void gemm_mfma(
    const u16* __restrict__ Ah, const u16* __restrict__ Al,
    MBatch gb, int M, int N, int K)
{
  const MSlot sl = gb.s[blockIdx.z];
  const int tid = threadIdx.x;
  const int w = tid >> 6, lane = tid & 63;
  const int fm = lane & 15, kg = lane >> 4;
  const int bm = blockIdx.x * 128, bn = blockIdx.y * 64;

  const size_t arow = (size_t)(bm + 32 * w + fm) * K + kg * 8;
  const u16* pa0h = Ah + arow;
  const u16* pa1h = pa0h + 16 * K;
  const u16* pa0l = Al + arow;
  const u16* pa1l = pa0l + 16 * K;
  const size_t brow = (size_t)(bn + fm) * K + kg * 8;
  const u16* pbh = sl.Wh + brow;
  const u16* pbl = sl.Wl + brow;

  f32x4 acc[2][4];
#pragma unroll
  for (int i = 0; i < 2; ++i)
#pragma unroll
    for (int j = 0; j < 4; ++j) acc[i][j] = (f32x4)(0.f);

#pragma unroll 2
  for (int ko = 0; ko < K; ko += 32) {
    bf16x8 a0h = *(const bf16x8*)(pa0h + ko);
    bf16x8 a1h = *(const bf16x8*)(pa1h + ko);
    bf16x8 a0l = *(const bf16x8*)(pa0l + ko);
    bf16x8 a1l = *(const bf16x8*)(pa1l + ko);
#pragma unroll
    for (int c = 0; c < 4; ++c) {
      bf16x8 bh = *(const bf16x8*)(pbh + (size_t)16 * c * K + ko);
      bf16x8 bl = *(const bf16x8*)(pbl + (size_t)16 * c * K + ko);
      acc[0][c] = __builtin_amdgcn_mfma_f32_16x16x32_bf16(a0h, bh, acc[0][c], 0, 0, 0);
      acc[0][c] = __builtin_amdgcn_mfma_f32_16x16x32_bf16(a0l, bh, acc[0][c], 0, 0, 0);
      acc[0][c] = __builtin_amdgcn_mfma_f32_16x16x32_bf16(a0h, bl, acc[0][c], 0, 0, 0);
      acc[1][c] = __builtin_amdgcn_mfma_f32_16x16x32_bf16(a1h, bh, acc[1][c], 0, 0, 0);
      acc[1][c] = __builtin_amdgcn_mfma_f32_16x16x32_bf16(a1l, bh, acc[1][c], 0, 0, 0);
      acc[1][c] = __builtin_amdgcn_mfma_f32_16x16x32_bf16(a1h, bl, acc[1][c], 0, 0, 0);
    }
  }

  const float* bias = sl.bias;
  float* out = sl.out;
  const int mode = sl.mode;
#pragma unroll
  for (int rt = 0; rt < 2; ++rt) {
#pragma unroll
    for (int c = 0; c < 4; ++c) {
      f32x4 v = acc[rt][c];
      const int n = bn + 16 * c + fm;
      const float bsv = bias[n];
#pragma unroll
      for (int r = 0; r < 4; ++r) {
        int m = bm + 32 * w + 16 * rt + kg * 4 + r;
        float cc = v[r] + bsv;
        if (mode >= 1) cc = silu_(cc);
        if (mode == 2) {
          int h = n >> 6, d = n & 63;
          int b = m >> 10, l = m & 1023;
          out[(((size_t)(b * 16 + h)) * 1024 + l) * 64 + d] = cc;
        } else {
          out[(size_t)m * N + n] = cc;
        }
      }
    }
  }
}

// ---------------------------------------------------------------------------
// Scalar projections: LDS-tiled (8 hs rows/block), packed scl[bh][t][8]
// ---------------------------------------------------------------------------
__global__ __launch_bounds__(256) void scalar_proj(
    const float* __restrict__ hs,
    const float* __restrict__ Wb,  const float* __restrict__ bb,
    const float* __restrict__ Wfd, const float* __restrict__ bfd, const float* __restrict__ fdb,
    const float* __restrict__ Wsd, const float* __restrict__ bsd, const float* __restrict__ sdb,
    const float* __restrict__ Wfg, const float* __restrict__ bfg,
    const float* __restrict__ Wsg, const float* __restrict__ bsg,
    float* __restrict__ scl)
{
  __shared__ float hl[8][1028];
  const int tid = threadIdx.x;
  const int m0 = blockIdx.x * 8;

#pragma unroll
  for (int i = 0; i < 8; ++i) {
    int f = tid + 256 * i;        // 0..2047 float4s
    int r = f >> 8;
    int c4 = f & 255;
    float4 v = *(const float4*)&hs[(size_t)(m0 + r) * 1024 + c4 * 4];
    *(float4*)&hl[r][c4 * 4] = v;
  }
  __syncthreads();

  for (int c = 0; c < 3; ++c) {
    int o = tid + 256 * c;
    if (o >= 640) break;
    int ml = o / 80;
    int cc = o - ml * 80;
    int type = cc >> 4;
    int h = cc & 15;
    const float* W; const float* bias; float extra = 0.f;
    switch (type) {
      case 0:  W = Wb;  bias = bb;  break;
      case 1:  W = Wfd; bias = bfd; extra = fdb[h]; break;
      case 2:  W = Wsd; bias = bsd; extra = sdb[h]; break;
      case 3:  W = Wfg; bias = bfg; break;
      default: W = Wsg; bias = bsg; break;
    }
    float s = 0.f;
    for (int k = 0; k < 1024; k += 4) {
      float4 hv = *(const float4*)&hl[ml][k];
      s = fmaf(hv.x, W[(k + 0) * 16 + h], s);
      s = fmaf(hv.y, W[(k + 1) * 16 + h], s);
      s = fmaf(hv.z, W[(k + 2) * 16 + h], s);
      s = fmaf(hv.w, W[(k + 3) * 16 + h], s);
    }
    s += bias[h] + extra;
    int m = m0 + ml;
    int b = m >> 10, l = m & 1023;
    scl[((size_t)((b * 16 + h) * 1024 + l)) * 8 + type] = sigm_(s);
  }
}

// ---------------------------------------------------------------------------
// Pre-normalize q and k in place: x *= rsqrt(sum_64(x^2)+1e-6).
// ---------------------------------------------------------------------------
__global__ __launch_bounds__(256) void prenorm(float* __restrict__ p)
{
  int wid = blockIdx.x * 4 + (threadIdx.x >> 6);
  int lane = threadIdx.x & 63;
  size_t idx = (size_t)wid * 64 + lane;
  float x = p[idx];
  float ss = x * x;
#pragma unroll
  for (int d2 = 32; d2 >= 1; d2 >>= 1) ss += __shfl_xor(ss, d2, 64);
  p[idx] = x * rsqrtf(ss + 1e-6f);
}

// ---------------------------------------------------------------------------
// Sequential scan, v13 (unchanged, 1094us, passed): 8 waves x 8 rows, one
// raw barrier/step, deferred cap (x-shfl spans the barrier), wave-specialized
// reduces, refold every 8 steps.
// ---------------------------------------------------------------------------
__global__ __launch_bounds__(512) void scan_kernel(
    const float* __restrict__ qg, const float* __restrict__ kg, const float* __restrict__ vg,
    const float* __restrict__ scl, const float* __restrict__ rfx, float* __restrict__ og)
{
  const int bh = blockIdx.x;     // 0..31
  const int tid = threadIdx.x;
  const int lane = tid & 63;     // column index
  const int w = tid >> 6;        // wave id 0..7: rows [8w, 8w+8)
  const float rf = rfx[0];
  const float rf2 = rf * rf;

  __shared__ float2 pE[2][8][64];  // {ef,es} partials, double-buffered
  __shared__ float2 pG[2][8][64];  // {gf,gs} partials
  __shared__ float4 xb[2];         // reduced x1,x2,x3 from wave 0

  float Sf[8], Ss[8];
#pragma unroll
  for (int j = 0; j < 8; ++j) { Sf[j] = 0.f; Ss[j] = 0.f; }

  const float* kb = kg + (size_t)bh * 65536;
  const float* qb = qg + (size_t)bh * 65536;
  const float* vb = vg + (size_t)bh * 65536;
  const float* sb = scl + (size_t)bh * 8192;
  const int b = bh >> 4, h = bh & 15;
  float* ob = og + (size_t)b * (1024 * 1024) + h * 64;  // + t*1024 + lane

  // ---- prologue ----
  float kv0 = kb[lane], qv0 = qb[lane];
  float kvA = kb[64 + lane], qvA = qb[64 + lane];   // t=1 per-lane
  float vv = vb[lane];
  float4 sc = *(const float4*)&sb[0];
  float sg4 = sb[4];

  float kr[8];
#pragma unroll
  for (int j = 0; j < 8; ++j) kr[j] = rdl_(kv0, w * 8 + j);

  float qkc = 0.f;
  if (w == 1) {
    float t0 = kv0 * qv0;
#pragma unroll
    for (int d2 = 32; d2 >= 1; d2 >>= 1) t0 += __shfl_xor(t0, d2, 64);
    qkc = t0;
  }

  float alf = 1.f, als = 1.f;          // actual = alpha * repr
  float Nf = 0.f, Ns = 0.f, Cc = 0.f;  // actual-scale norm trackers
  float fdp = 1.f, sdp = 1.f;          // fd/sd of previous step (for chain)
  float fgp = 0.f, sgp = 0.f;          // gates of previous step
  float ofp = 0.f, osp = 0.f;          // deferred output dots (repr)
  float ef = 0.f, es = 0.f, gf = 0.f, gs = 0.f;

  for (int t = 0; t < 1024; ++t) {
    const int t1 = (t + 1) & 1023;
    const int t2 = (t + 2) & 1023;

    // ---- raw barrier: LDS-visibility only ----
    if (t > 0) {
      asm volatile("s_waitcnt lgkmcnt(0)" ::: "memory");
      __builtin_amdgcn_s_barrier();
    }

    // ---- prefetch ----
    const float kvB = kb[t2 * 64 + lane];
    const float qvB = qb[t2 * 64 + lane];
    const float vn  = vb[t1 * 64 + lane];
    const float4 scn = *(const float4*)&sb[(size_t)t1 * 8];
    const float sgn = sb[(size_t)t1 * 8 + 4];

    // ---- read partials + finish previous step's cap chain ----
    if (t > 0) {
      const int pr = (t - 1) & 1;
      float2 e0 = pE[pr][0][lane], e1 = pE[pr][1][lane];
      float2 e2 = pE[pr][2][lane], e3 = pE[pr][3][lane];
      float2 e4 = pE[pr][4][lane], e5 = pE[pr][5][lane];
      float2 e6 = pE[pr][6][lane], e7 = pE[pr][7][lane];
      float2 g0 = pG[pr][0][lane], g1 = pG[pr][1][lane];
      float2 g2 = pG[pr][2][lane], g3 = pG[pr][3][lane];
      float2 g4 = pG[pr][4][lane], g5 = pG[pr][5][lane];
      float2 g6 = pG[pr][6][lane], g7 = pG[pr][7][lane];
      ef = ((e0.x + e1.x) + (e2.x + e3.x)) + ((e4.x + e5.x) + (e6.x + e7.x));
      es = ((e0.y + e1.y) + (e2.y + e3.y)) + ((e4.y + e5.y) + (e6.y + e7.y));
      gf = ((g0.x + g1.x) + (g2.x + g3.x)) + ((g4.x + g5.x) + (g6.x + g7.x));
      gs = ((g0.y + g1.y) + (g2.y + g3.y)) + ((g4.y + g5.y) + (g6.y + g7.y));
      const float4 xv = xb[pr];
      const float Nfd = fmaf(fdp * fdp, Nf, xv.x);
      const float Nsd = fmaf(sdp * sdp, Ns, xv.y);
      const float Cd  = fmaf(fdp * sdp, Cc, xv.z);
      const float NTf = Nfd + 2.f * rf * Cd + rf2 * Nsd;
      const float NTs = Nsd + 2.f * rf * Cd + rf2 * Nfd;
      const float CT  = (1.f + rf2) * Cd + rf * (Nfd + Nsd);
      const bool capf = NTf > 4096.f;
      const bool caps = NTs > 4096.f;
      const float scf = capf ? 64.f * rsqrtf(NTf) : 1.f;
      const float scs = caps ? 64.f * rsqrtf(NTs) : 1.f;
      Nf = capf ? 4096.f : NTf;
      Ns = caps ? 4096.f : NTs;
      Cc = scf * scs * CT;
      alf *= scf; als *= scs;
      // deferred output for step t-1 (actual scale now known)
      if (w == 1)
        ob[(size_t)(t - 1) * 1024 + lane] = fgp * alf * ofp + sgp * als * osp;
    }

    const float bt = sc.x, fdt = sc.y, sdt = sc.z, fgt = sc.w, sgt = sg4;

    // ---- head: decayed scales, error, coefficients (repr) ----
    const float d_f = alf * fdt, d_s = als * sdt;
    const float EF = d_f * ef, ES = d_s * es;
    const float errf = vv - EF, errs = vv - ES;
    const float rdf = 1.f / d_f, rds = 1.f / d_s;
    const float beff = bt * errf * rdf;
    const float bess = bt * errs * rds;
    const float cfs = rf * d_s * rdf;
    const float csf = rf * d_f * rds;

    // ---- x-values for this step's cap (wave 0 only; spans the barrier) ----
    float x1 = 0.f, x2 = 0.f, x3 = 0.f;
    if (w == 0) {
      x1 = bt * errf * fmaf(bt, errf, 2.f * EF);
      x2 = bt * errs * fmaf(bt, errs, 2.f * ES);
      x3 = bt * (fmaf(bt, errf * errs, errs * EF) + errf * ES);
#pragma unroll
      for (int d2 = 32; d2 >= 1; d2 >>= 1) {
        x1 += __shfl_xor(x1, d2, 64);
        x2 += __shfl_xor(x2, d2, 64);
        x3 += __shfl_xor(x3, d2, 64);
      }
    }

    // ---- qk for t+1 + analytic output dots (wave 1 only) ----
    float qkn = 0.f, of_new = 0.f, os_new = 0.f;
    if (w == 1) {
      float t0 = kvA * qvA;
#pragma unroll
      for (int d2 = 32; d2 >= 1; d2 >>= 1) t0 += __shfl_xor(t0, d2, 64);
      qkn = t0;
      const float sfq = fmaf(qkc, beff, gf);
      const float svq = fmaf(qkc, bess, gs);
      of_new = fmaf(cfs, svq, sfq);   // q . Tf (repr)
      os_new = fmaf(csf, sfq, svq);
    }

    // ---- broadcast rows of k_{t+1}, q_{t+1} ----
    float kr1[8], qr1[8];
#pragma unroll
    for (int j = 0; j < 8; ++j) {
      kr1[j] = rdl_(kvA, w * 8 + j);
      qr1[j] = rdl_(qvA, w * 8 + j);
    }

    // ---- register pass: update + combine + fused t+1 dots ----
    float ef1 = 0.f, es1 = 0.f, gf1 = 0.f, gs1 = 0.f;
#pragma unroll
    for (int j = 0; j < 8; ++j) {
      float sfv = fmaf(kr[j], beff, Sf[j]);
      float svv = fmaf(kr[j], bess, Ss[j]);
      float tf = fmaf(cfs, svv, sfv);
      float ts = fmaf(csf, sfv, svv);
      ef1 = fmaf(kr1[j], tf, ef1);
      es1 = fmaf(kr1[j], ts, es1);
      gf1 = fmaf(qr1[j], tf, gf1);
      gs1 = fmaf(qr1[j], ts, gs1);
      Sf[j] = tf; Ss[j] = ts;
    }

    // ---- absorb decay into alpha; refold every 8 steps ----
    alf = d_f; als = d_s;
    if ((t & 7) == 7) {
#pragma unroll
      for (int j = 0; j < 8; ++j) { Sf[j] *= alf; Ss[j] *= als; }
      ef1 *= alf; gf1 *= alf; es1 *= als; gs1 *= als;
      of_new *= alf; os_new *= als;
      alf = 1.f; als = 1.f;
    }

    // ---- write partials + publish reduced x ----
    const int par = t & 1;
    pE[par][w][lane] = make_float2(ef1, es1);
    pG[par][w][lane] = make_float2(gf1, gs1);
    if (w == 0 && lane == 0) xb[par] = make_float4(x1, x2, x3, 0.f);

    // ---- rotate pipeline ----
#pragma unroll
    for (int j = 0; j < 8; ++j) kr[j] = kr1[j];
    kvA = kvB; qvA = qvB; vv = vn; sc = scn; sg4 = sgn; qkc = qkn;
    fdp = fdt; sdp = sdt; fgp = fgt; sgp = sgt;
    ofp = of_new; osp = os_new;
  }

  // ---- epilogue: finish cap for t=1023 and write its output ----
  asm volatile("s_waitcnt lgkmcnt(0)" ::: "memory");
  __builtin_amdgcn_s_barrier();
  if (w == 1) {
    const float4 xv = xb[1023 & 1];
    const float Nfd = fmaf(fdp * fdp, Nf, xv.x);
    const float Nsd = fmaf(sdp * sdp, Ns, xv.y);
    const float Cd  = fmaf(fdp * sdp, Cc, xv.z);
    const float NTf = Nfd + 2.f * rf * Cd + rf2 * Nsd;
    const float NTs = Nsd + 2.f * rf * Cd + rf2 * Nfd;
    const float scf = (NTf > 4096.f) ? 64.f * rsqrtf(NTf) : 1.f;
    const float scs = (NTs > 4096.f) ? 64.f * rsqrtf(NTs) : 1.f;
    alf *= scf; als *= scs;
    ob[(size_t)1023 * 1024 + lane] = fgp * alf * ofp + sgp * als * osp;
  }
}

// ---------------------------------------------------------------------------
// Gated RMSNorm: og = o * rsqrt(mean(o^2)+eps) * onorm_w * silu_g (g pre-silu'd)
// ---------------------------------------------------------------------------
__global__ __launch_bounds__(256) void rms_gate(
    const float* __restrict__ o, const float* __restrict__ gsil,
    const float* __restrict__ onw, float* __restrict__ og)
{
  int gi = blockIdx.x * 4 + (threadIdx.x >> 6);
  int lane = threadIdx.x & 63;
  size_t idx = (size_t)gi * 64 + lane;
  float x = o[idx];
  float ss = x * x;
#pragma unroll
  for (int d2 = 32; d2 >= 1; d2 >>= 1) ss += __shfl_xor(ss, d2, 64);
  float r = rsqrtf(ss * (1.f / 64.f) + 1e-5f);
  og[idx] = x * r * onw[lane] * gsil[idx];
}

// ---------------------------------------------------------------------------
// Host launcher
// ---------------------------------------------------------------------------
extern "C" void kernel_launch(void* const* d_in, const int* in_sizes, int n_in,
                              void* d_out, int out_size, void* d_ws, size_t ws_size,
                              hipStream_t stream)
{
  const float* hs  = (const float*)d_in[0];
  const float* Wq  = (const float*)d_in[1];
  const float* bq  = (const float*)d_in[2];
  const float* Wk  = (const float*)d_in[3];
  const float* bk  = (const float*)d_in[4];
  const float* Wv  = (const float*)d_in[5];
  const float* bv  = (const float*)d_in[6];
  const float* Wb  = (const float*)d_in[7];
  const float* bb  = (const float*)d_in[8];
  const float* Wfd = (const float*)d_in[9];
  const float* bfd = (const float*)d_in[10];
  const float* fdb = (const float*)d_in[11];
  const float* Wsd = (const float*)d_in[12];
  const float* bsd = (const float*)d_in[13];
  const float* sdb = (const float*)d_in[14];
  const float* Wfg = (const float*)d_in[15];
  const float* bfg = (const float*)d_in[16];
  const float* Wsg = (const float*)d_in[17];
  const float* bsg = (const float*)d_in[18];
  const float* Wg  = (const float*)d_in[19];
  const float* bg  = (const float*)d_in[20];
  const float* onw = (const float*)d_in[21];
  const float* Wo  = (const float*)d_in[22];
  const float* bo  = (const float*)d_in[23];
  const float* rfx = (const float*)d_in[24];

  float* ws = (float*)d_ws;
  const size_t TWO_M = (size_t)1 << 21;  // 2M floats = B*H*L*64 = B*L*D
  float* q_ws  = ws;
  float* k_ws  = ws + TWO_M;
  float* v_ws  = ws + 2 * TWO_M;
  float* g_ws  = ws + 3 * TWO_M;
  float* o_ws  = ws + 4 * TWO_M;
  float* scl_ws = ws + 5 * TWO_M;            // 262144 floats
  u16*   wt    = (u16*)(ws + 5 * TWO_M + 262144);  // 5 x (1M hi + 1M lo) u16
  // hs split overlays o_ws (free until scan); og split overlays v_ws (free after scan)
  u16* hs_hi = (u16*)o_ws;
  u16* hs_lo = (u16*)(o_ws + TWO_M / 2);
  u16* og_hi = (u16*)v_ws;
  u16* og_lo = (u16*)(v_ws + TWO_M / 2);
  float* og_f = q_ws;                        // rms output f32 (q free after scan)

  const size_t WSZ = 1048576;  // 1024*1024 elems per W matrix
  u16* WqTh = wt;               u16* WqTl = wt + WSZ;
  u16* WkTh = wt + 2 * WSZ;     u16* WkTl = wt + 3 * WSZ;
  u16* WvTh = wt + 4 * WSZ;     u16* WvTl = wt + 5 * WSZ;
  u16* WgTh = wt + 6 * WSZ;     u16* WgTl = wt + 7 * WSZ;
  u16* WoTh = wt + 8 * WSZ;     u16* WoTl = wt + 9 * WSZ;

  // 0) split hs into bf16 hi/lo (into o_ws region)
  split_mk<<<2048, 256, 0, stream>>>(hs, hs_hi, hs_lo, (int)(TWO_M / 4));

  // 0b) transpose + split the 5 big weight matrices
  WSplitBatch wb;
  wb.s[0] = { Wq, WqTh, WqTl };
  wb.s[1] = { Wk, WkTh, WkTl };
  wb.s[2] = { Wv, WvTh, WvTl };
  wb.s[3] = { Wg, WgTh, WgTl };
  wb.s[4] = { Wo, WoTh, WoTl };
  splitT<<<dim3(32, 32, 5), 256, 0, stream>>>(wb);

  // 1) big projections via split-bf16 MFMA: q,k,v (silu+scatter), g (silu)
  MBatch gb1;
  gb1.s[0] = { WqTh, WqTl, bq, q_ws, 2 };
  gb1.s[1] = { WkTh, WkTl, bk, k_ws, 2 };
  gb1.s[2] = { WvTh, WvTl, bv, v_ws, 2 };
  gb1.s[3] = { WgTh, WgTl, bg, g_ws, 1 };
  gemm_mfma<<<dim3(16, 16, 4), 256, 0, stream>>>(hs_hi, hs_lo, gb1, 2048, 1024, 1024);

  // 2) per-head scalar projections (fp32, LDS-tiled)
  scalar_proj<<<256, 256, 0, stream>>>(hs, Wb, bb, Wfd, bfd, fdb, Wsd, bsd, sdb,
                                       Wfg, bfg, Wsg, bsg, scl_ws);

  // 3) pre-normalize q,k (contiguous 4M floats = 65536 rows of 64)
  prenorm<<<16384, 256, 0, stream>>>(q_ws);

  // 4) sequential dual-state delta-rule scan (unchanged r13)
  scan_kernel<<<32, 512, 0, stream>>>(q_ws, k_ws, v_ws, scl_ws, rfx, o_ws);

  // 5) gated RMSNorm -> og_f (q_ws)
  rms_gate<<<8192, 256, 0, stream>>>(o_ws, g_ws, onw, og_f);

  // 5b) split og into bf16 hi/lo (into v_ws region)
  split_mk<<<2048, 256, 0, stream>>>(og_f, og_hi, og_lo, (int)(TWO_M / 4));

  // 6) output projection via split-bf16 MFMA -> d_out
  MBatch gb2;
  gb2.s[0] = { WoTh, WoTl, bo, (float*)d_out, 0 };
  gb2.s[1] = gb2.s[0]; gb2.s[2] = gb2.s[0]; gb2.s[3] = gb2.s[0];
  gemm_mfma<<<dim3(16, 16, 1), 256, 0, stream>>>(og_hi, og_lo, gb2, 2048, 1024, 1024);
}

// Round 17
// 1379.868 us; speedup vs baseline: 1.2326x; 1.0082x over previous
//
#include <hip/hip_runtime.h>

// ---------------------------------------------------------------------------
// Problem constants: B=2, L=1024, D=1024, H=16, DK=DV=64
// ---------------------------------------------------------------------------

typedef unsigned short u16;
typedef u16  u16x4 __attribute__((ext_vector_type(4)));
typedef short bf16x8 __attribute__((ext_vector_type(8)));
typedef float f32x4 __attribute__((ext_vector_type(4)));

struct MSlot { const u16* Wh; const u16* Wl; const float* bias; float* out; int mode; };
struct MBatch { MSlot s[4]; };
struct WSplitSlot { const float* W; u16* Th; u16* Tl; };
struct WSplitBatch { WSplitSlot s[5]; };

__device__ __forceinline__ float silu_(float x) {
  return x / (1.f + __expf(-x));
}
__device__ __forceinline__ float sigm_(float x) {
  return 1.f / (1.f + __expf(-x));
}
__device__ __forceinline__ float rdl_(float v, int l) {
  return __int_as_float(__builtin_amdgcn_readlane(__float_as_int(v), l));
}
// round-to-nearest-even bf16 split: x ~= hi + lo (each bf16), err ~ x*2^-17
__device__ __forceinline__ void split2_(float x, u16& h, u16& l) {
  unsigned u = __float_as_uint(x);
  unsigned r = (u + 0x7FFFu + ((u >> 16) & 1u)) >> 16;
  h = (u16)r;
  float lo = x - __uint_as_float(r << 16);
  unsigned u2 = __float_as_uint(lo);
  unsigned r2 = (u2 + 0x7FFFu + ((u2 >> 16) & 1u)) >> 16;
  l = (u16)r2;
}

// ---------------------------------------------------------------------------
// split_mk: X[n] f32 -> H[n], L[n] bf16 (hi/lo), float4-vectorized.
// ---------------------------------------------------------------------------
__global__ __launch_bounds__(256) void split_mk(
    const float* __restrict__ X, u16* __restrict__ H, u16* __restrict__ L, int n4)
{
  int i = blockIdx.x * 256 + threadIdx.x;
  if (i >= n4) return;
  float4 x = ((const float4*)X)[i];
  u16 h0, h1, h2, h3, l0, l1, l2, l3;
  split2_(x.x, h0, l0);
  split2_(x.y, h1, l1);
  split2_(x.z, h2, l2);
  split2_(x.w, h3, l3);
  u16x4 h, l;
  h.x = h0; h.y = h1; h.z = h2; h.w = h3;
  l.x = l0; l.y = l1; l.z = l2; l.w = l3;
  ((u16x4*)H)[i] = h;
  ((u16x4*)L)[i] = l;
}

// ---------------------------------------------------------------------------
// splitT: W[1024][1024] f32 -> Th[N][K], Tl[N][K] bf16 (transposed + split).
// ---------------------------------------------------------------------------
__global__ __launch_bounds__(256) void splitT(WSplitBatch wb)
{
  const WSplitSlot sl = wb.s[blockIdx.z];
  __shared__ float tl[32][33];
  const int tid = threadIdx.x;
  const int k0 = blockIdx.x * 32, n0 = blockIdx.y * 32;
  const int c = tid & 31, r8 = tid >> 5;
#pragma unroll
  for (int j = 0; j < 4; ++j) {
    int r = r8 + 8 * j;
    tl[r][c] = sl.W[(size_t)(k0 + r) * 1024 + n0 + c];
  }
  __syncthreads();
#pragma unroll
  for (int j = 0; j < 4; ++j) {
    int nr = r8 + 8 * j;
    float x = tl[c][nr];
    u16 h, l;
    split2_(x, h, l);
    sl.Th[(size_t)(n0 + nr) * 1024 + k0 + c] = h;
    sl.Tl[(size_t)(n0 + nr) * 1024 + k0 + c] = l;
  }
}

// ---------------------------------------------------------------------------
// Split-bf16 MFMA GEMM v2: register double-buffered fragment loads.
// Per K-step: 12 x 16B loads (next step) issued BEFORE the 24 MFMAs of the
// current step -> ~200cyc of MFMA cover for the L2 latency (r16 was
// latency-exposed at ~320 TF effective). Layouts as r16 (verified, passed).
// ---------------------------------------------------------------------------
__global__ __launch_bounds__(256) void gemm_mfma(
    const u16* __restrict__ Ah, const u16* __restrict__ Al,
    MBatch gb, int M, int N, int K)
{
  const MSlot sl = gb.s[blockIdx.z];
  const int tid = threadIdx.x;
  const int w = tid >> 6, lane = tid & 63;
  const int fm = lane & 15, kg = lane >> 4;
  const int bm = blockIdx.x * 128, bn = blockIdx.y * 64;

  const size_t arow = (size_t)(bm + 32 * w + fm) * K + kg * 8;
  const u16* pa0h = Ah + arow;
  const u16* pa1h = pa0h + 16 * K;
  const u16* pa0l = Al + arow;
  const u16* pa1l = pa0l + 16 * K;
  const size_t brow = (size_t)(bn + fm) * K + kg * 8;
  const u16* pbh = sl.Wh + brow;
  const u16* pbl = sl.Wl + brow;

  f32x4 acc[2][4];
#pragma unroll
  for (int i = 0; i < 2; ++i)
#pragma unroll
    for (int j = 0; j < 4; ++j) acc[i][j] = (f32x4)(0.f);

  // current-step fragments
  bf16x8 a0h = *(const bf16x8*)(pa0h);
  bf16x8 a1h = *(const bf16x8*)(pa1h);
  bf16x8 a0l = *(const bf16x8*)(pa0l);
  bf16x8 a1l = *(const bf16x8*)(pa1l);
  bf16x8 bh[4], bl[4];
#pragma unroll
  for (int c = 0; c < 4; ++c) {
    bh[c] = *(const bf16x8*)(pbh + (size_t)16 * c * K);
    bl[c] = *(const bf16x8*)(pbl + (size_t)16 * c * K);
  }

  for (int ko = 0; ko < K; ko += 32) {
    // ---- preload next step's 12 fragments (cover under MFMAs below) ----
    bf16x8 na0h, na1h, na0l, na1l, nbh[4], nbl[4];
    const int kn = ko + 32;
    if (kn < K) {
      na0h = *(const bf16x8*)(pa0h + kn);
      na1h = *(const bf16x8*)(pa1h + kn);
      na0l = *(const bf16x8*)(pa0l + kn);
      na1l = *(const bf16x8*)(pa1l + kn);
#pragma unroll
      for (int c = 0; c < 4; ++c) {
        nbh[c] = *(const bf16x8*)(pbh + (size_t)16 * c * K + kn);
        nbl[c] = *(const bf16x8*)(pbl + (size_t)16 * c * K + kn);
      }
    }
    // ---- 24 MFMAs on current fragments ----
#pragma unroll
    for (int c = 0; c < 4; ++c) {
      acc[0][c] = __builtin_amdgcn_mfma_f32_16x16x32_bf16(a0h, bh[c], acc[0][c], 0, 0, 0);
      acc[0][c] = __builtin_amdgcn_mfma_f32_16x16x32_bf16(a0l, bh[c], acc[0][c], 0, 0, 0);
      acc[0][c] = __builtin_amdgcn_mfma_f32_16x16x32_bf16(a0h, bl[c], acc[0][c], 0, 0, 0);
      acc[1][c] = __builtin_amdgcn_mfma_f32_16x16x32_bf16(a1h, bh[c], acc[1][c], 0, 0, 0);
      acc[1][c] = __builtin_amdgcn_mfma_f32_16x16x32_bf16(a1l, bh[c], acc[1][c], 0, 0, 0);
      acc[1][c] = __builtin_amdgcn_mfma_f32_16x16x32_bf16(a1h, bl[c], acc[1][c], 0, 0, 0);
    }
    // ---- rotate ----
    if (kn < K) {
      a0h = na0h; a1h = na1h; a0l = na0l; a1l = na1l;
#pragma unroll
      for (int c = 0; c < 4; ++c) { bh[c] = nbh[c]; bl[c] = nbl[c]; }
    }
  }

  const float* bias = sl.bias;
  float* out = sl.out;
  const int mode = sl.mode;
#pragma unroll
  for (int rt = 0; rt < 2; ++rt) {
#pragma unroll
    for (int c = 0; c < 4; ++c) {
      f32x4 v = acc[rt][c];
      const int n = bn + 16 * c + fm;
      const float bsv = bias[n];
#pragma unroll
      for (int r = 0; r < 4; ++r) {
        int m = bm + 32 * w + 16 * rt + kg * 4 + r;
        float cc = v[r] + bsv;
        if (mode >= 1) cc = silu_(cc);
        if (mode == 2) {
          int h = n >> 6, d = n & 63;
          int b = m >> 10, l = m & 1023;
          out[(((size_t)(b * 16 + h)) * 1024 + l) * 64 + d] = cc;
        } else {
          out[(size_t)m * N + n] = cc;
        }
      }
    }
  }
}

// ---------------------------------------------------------------------------
// Scalar projections: LDS-tiled (8 hs rows/block), packed scl[bh][t][8]
// ---------------------------------------------------------------------------
__global__ __launch_bounds__(256) void scalar_proj(
    const float* __restrict__ hs,
    const float* __restrict__ Wb,  const float* __restrict__ bb,
    const float* __restrict__ Wfd, const float* __restrict__ bfd, const float* __restrict__ fdb,
    const float* __restrict__ Wsd, const float* __restrict__ bsd, const float* __restrict__ sdb,
    const float* __restrict__ Wfg, const float* __restrict__ bfg,
    const float* __restrict__ Wsg, const float* __restrict__ bsg,
    float* __restrict__ scl)
{
  __shared__ float hl[8][1028];
  const int tid = threadIdx.x;
  const int m0 = blockIdx.x * 8;

#pragma unroll
  for (int i = 0; i < 8; ++i) {
    int f = tid + 256 * i;
    int r = f >> 8;
    int c4 = f & 255;
    float4 v = *(const float4*)&hs[(size_t)(m0 + r) * 1024 + c4 * 4];
    *(float4*)&hl[r][c4 * 4] = v;
  }
  __syncthreads();

  for (int c = 0; c < 3; ++c) {
    int o = tid + 256 * c;
    if (o >= 640) break;
    int ml = o / 80;
    int cc = o - ml * 80;
    int type = cc >> 4;
    int h = cc & 15;
    const float* W; const float* bias; float extra = 0.f;
    switch (type) {
      case 0:  W = Wb;  bias = bb;  break;
      case 1:  W = Wfd; bias = bfd; extra = fdb[h]; break;
      case 2:  W = Wsd; bias = bsd; extra = sdb[h]; break;
      case 3:  W = Wfg; bias = bfg; break;
      default: W = Wsg; bias = bsg; break;
    }
    float s = 0.f;
    for (int k = 0; k < 1024; k += 4) {
      float4 hv = *(const float4*)&hl[ml][k];
      s = fmaf(hv.x, W[(k + 0) * 16 + h], s);
      s = fmaf(hv.y, W[(k + 1) * 16 + h], s);
      s = fmaf(hv.z, W[(k + 2) * 16 + h], s);
      s = fmaf(hv.w, W[(k + 3) * 16 + h], s);
    }
    s += bias[h] + extra;
    int m = m0 + ml;
    int b = m >> 10, l = m & 1023;
    scl[((size_t)((b * 16 + h) * 1024 + l)) * 8 + type] = sigm_(s);
  }
}

// ---------------------------------------------------------------------------
// Pre-normalize q and k in place: x *= rsqrt(sum_64(x^2)+1e-6).
// ---------------------------------------------------------------------------
__global__ __launch_bounds__(256) void prenorm(float* __restrict__ p)
{
  int wid = blockIdx.x * 4 + (threadIdx.x >> 6);
  int lane = threadIdx.x & 63;
  size_t idx = (size_t)wid * 64 + lane;
  float x = p[idx];
  float ss = x * x;
#pragma unroll
  for (int d2 = 32; d2 >= 1; d2 >>= 1) ss += __shfl_xor(ss, d2, 64);
  p[idx] = x * rsqrtf(ss + 1e-6f);
}

// ---------------------------------------------------------------------------
// Sequential scan, v13 (unchanged, 1094us, passed).
// ---------------------------------------------------------------------------
__global__ __launch_bounds__(512) void scan_kernel(
    const float* __restrict__ qg, const float* __restrict__ kg, const float* __restrict__ vg,
    const float* __restrict__ scl, const float* __restrict__ rfx, float* __restrict__ og)
{
  const int bh = blockIdx.x;     // 0..31
  const int tid = threadIdx.x;
  const int lane = tid & 63;     // column index
  const int w = tid >> 6;        // wave id 0..7: rows [8w, 8w+8)
  const float rf = rfx[0];
  const float rf2 = rf * rf;

  __shared__ float2 pE[2][8][64];
  __shared__ float2 pG[2][8][64];
  __shared__ float4 xb[2];

  float Sf[8], Ss[8];
#pragma unroll
  for (int j = 0; j < 8; ++j) { Sf[j] = 0.f; Ss[j] = 0.f; }

  const float* kb = kg + (size_t)bh * 65536;
  const float* qb = qg + (size_t)bh * 65536;
  const float* vb = vg + (size_t)bh * 65536;
  const float* sb = scl + (size_t)bh * 8192;
  const int b = bh >> 4, h = bh & 15;
  float* ob = og + (size_t)b * (1024 * 1024) + h * 64;

  float kv0 = kb[lane], qv0 = qb[lane];
  float kvA = kb[64 + lane], qvA = qb[64 + lane];
  float vv = vb[lane];
  float4 sc = *(const float4*)&sb[0];
  float sg4 = sb[4];

  float kr[8];
#pragma unroll
  for (int j = 0; j < 8; ++j) kr[j] = rdl_(kv0, w * 8 + j);

  float qkc = 0.f;
  if (w == 1) {
    float t0 = kv0 * qv0;
#pragma unroll
    for (int d2 = 32; d2 >= 1; d2 >>= 1) t0 += __shfl_xor(t0, d2, 64);
    qkc = t0;
  }

  float alf = 1.f, als = 1.f;
  float Nf = 0.f, Ns = 0.f, Cc = 0.f;
  float fdp = 1.f, sdp = 1.f;
  float fgp = 0.f, sgp = 0.f;
  float ofp = 0.f, osp = 0.f;
  float ef = 0.f, es = 0.f, gf = 0.f, gs = 0.f;

  for (int t = 0; t < 1024; ++t) {
    const int t1 = (t + 1) & 1023;
    const int t2 = (t + 2) & 1023;

    if (t > 0) {
      asm volatile("s_waitcnt lgkmcnt(0)" ::: "memory");
      __builtin_amdgcn_s_barrier();
    }

    const float kvB = kb[t2 * 64 + lane];
    const float qvB = qb[t2 * 64 + lane];
    const float vn  = vb[t1 * 64 + lane];
    const float4 scn = *(const float4*)&sb[(size_t)t1 * 8];
    const float sgn = sb[(size_t)t1 * 8 + 4];

    if (t > 0) {
      const int pr = (t - 1) & 1;
      float2 e0 = pE[pr][0][lane], e1 = pE[pr][1][lane];
      float2 e2 = pE[pr][2][lane], e3 = pE[pr][3][lane];
      float2 e4 = pE[pr][4][lane], e5 = pE[pr][5][lane];
      float2 e6 = pE[pr][6][lane], e7 = pE[pr][7][lane];
      float2 g0 = pG[pr][0][lane], g1 = pG[pr][1][lane];
      float2 g2 = pG[pr][2][lane], g3 = pG[pr][3][lane];
      float2 g4 = pG[pr][4][lane], g5 = pG[pr][5][lane];
      float2 g6 = pG[pr][6][lane], g7 = pG[pr][7][lane];
      ef = ((e0.x + e1.x) + (e2.x + e3.x)) + ((e4.x + e5.x) + (e6.x + e7.x));
      es = ((e0.y + e1.y) + (e2.y + e3.y)) + ((e4.y + e5.y) + (e6.y + e7.y));
      gf = ((g0.x + g1.x) + (g2.x + g3.x)) + ((g4.x + g5.x) + (g6.x + g7.x));
      gs = ((g0.y + g1.y) + (g2.y + g3.y)) + ((g4.y + g5.y) + (g6.y + g7.y));
      const float4 xv = xb[pr];
      const float Nfd = fmaf(fdp * fdp, Nf, xv.x);
      const float Nsd = fmaf(sdp * sdp, Ns, xv.y);
      const float Cd  = fmaf(fdp * sdp, Cc, xv.z);
      const float NTf = Nfd + 2.f * rf * Cd + rf2 * Nsd;
      const float NTs = Nsd + 2.f * rf * Cd + rf2 * Nfd;
      const float CT  = (1.f + rf2) * Cd + rf * (Nfd + Nsd);
      const bool capf = NTf > 4096.f;
      const bool caps = NTs > 4096.f;
      const float scf = capf ? 64.f * rsqrtf(NTf) : 1.f;
      const float scs = caps ? 64.f * rsqrtf(NTs) : 1.f;
      Nf = capf ? 4096.f : NTf;
      Ns = caps ? 4096.f : NTs;
      Cc = scf * scs * CT;
      alf *= scf; als *= scs;
      if (w == 1)
        ob[(size_t)(t - 1) * 1024 + lane] = fgp * alf * ofp + sgp * als * osp;
    }

    const float bt = sc.x, fdt = sc.y, sdt = sc.z, fgt = sc.w, sgt = sg4;

    const float d_f = alf * fdt, d_s = als * sdt;
    const float EF = d_f * ef, ES = d_s * es;
    const float errf = vv - EF, errs = vv - ES;
    const float rdf = 1.f / d_f, rds = 1.f / d_s;
    const float beff = bt * errf * rdf;
    const float bess = bt * errs * rds;
    const float cfs = rf * d_s * rdf;
    const float csf = rf * d_f * rds;

    float x1 = 0.f, x2 = 0.f, x3 = 0.f;
    if (w == 0) {
      x1 = bt * errf * fmaf(bt, errf, 2.f * EF);
      x2 = bt * errs * fmaf(bt, errs, 2.f * ES);
      x3 = bt * (fmaf(bt, errf * errs, errs * EF) + errf * ES);
#pragma unroll
      for (int d2 = 32; d2 >= 1; d2 >>= 1) {
        x1 += __shfl_xor(x1, d2, 64);
        x2 += __shfl_xor(x2, d2, 64);
        x3 += __shfl_xor(x3, d2, 64);
      }
    }

    float qkn = 0.f, of_new = 0.f, os_new = 0.f;
    if (w == 1) {
      float t0 = kvA * qvA;
#pragma unroll
      for (int d2 = 32; d2 >= 1; d2 >>= 1) t0 += __shfl_xor(t0, d2, 64);
      qkn = t0;
      const float sfq = fmaf(qkc, beff, gf);
      const float svq = fmaf(qkc, bess, gs);
      of_new = fmaf(cfs, svq, sfq);
      os_new = fmaf(csf, sfq, svq);
    }

    float kr1[8], qr1[8];
#pragma unroll
    for (int j = 0; j < 8; ++j) {
      kr1[j] = rdl_(kvA, w * 8 + j);
      qr1[j] = rdl_(qvA, w * 8 + j);
    }

    float ef1 = 0.f, es1 = 0.f, gf1 = 0.f, gs1 = 0.f;
#pragma unroll
    for (int j = 0; j < 8; ++j) {
      float sfv = fmaf(kr[j], beff, Sf[j]);
      float svv = fmaf(kr[j], bess, Ss[j]);
      float tf = fmaf(cfs, svv, sfv);
      float ts = fmaf(csf, sfv, svv);
      ef1 = fmaf(kr1[j], tf, ef1);
      es1 = fmaf(kr1[j], ts, es1);
      gf1 = fmaf(qr1[j], tf, gf1);
      gs1 = fmaf(qr1[j], ts, gs1);
      Sf[j] = tf; Ss[j] = ts;
    }

    alf = d_f; als = d_s;
    if ((t & 7) == 7) {
#pragma unroll
      for (int j = 0; j < 8; ++j) { Sf[j] *= alf; Ss[j] *= als; }
      ef1 *= alf; gf1 *= alf; es1 *= als; gs1 *= als;
      of_new *= alf; os_new *= als;
      alf = 1.f; als = 1.f;
    }

    const int par = t & 1;
    pE[par][w][lane] = make_float2(ef1, es1);
    pG[par][w][lane] = make_float2(gf1, gs1);
    if (w == 0 && lane == 0) xb[par] = make_float4(x1, x2, x3, 0.f);

#pragma unroll
    for (int j = 0; j < 8; ++j) kr[j] = kr1[j];
    kvA = kvB; qvA = qvB; vv = vn; sc = scn; sg4 = sgn; qkc = qkn;
    fdp = fdt; sdp = sdt; fgp = fgt; sgp = sgt;
    ofp = of_new; osp = os_new;
  }

  asm volatile("s_waitcnt lgkmcnt(0)" ::: "memory");
  __builtin_amdgcn_s_barrier();
  if (w == 1) {
    const float4 xv = xb[1023 & 1];
    const float Nfd = fmaf(fdp * fdp, Nf, xv.x);
    const float Nsd = fmaf(sdp * sdp, Ns, xv.y);
    const float Cd  = fmaf(fdp * sdp, Cc, xv.z);
    const float NTf = Nfd + 2.f * rf * Cd + rf2 * Nsd;
    const float NTs = Nsd + 2.f * rf * Cd + rf2 * Nfd;
    const float scf = (NTf > 4096.f) ? 64.f * rsqrtf(NTf) : 1.f;
    const float scs = (NTs > 4096.f) ? 64.f * rsqrtf(NTs) : 1.f;
    alf *= scf; als *= scs;
    ob[(size_t)1023 * 1024 + lane] = fgp * alf * ofp + sgp * als * osp;
  }
}

// ---------------------------------------------------------------------------
// Gated RMSNorm + bf16 hi/lo split fused: og_hi/og_lo directly (no f32 pass).
// ---------------------------------------------------------------------------
__global__ __launch_bounds__(256) void rms_gate_split(
    const float* __restrict__ o, const float* __restrict__ gsil,
    const float* __restrict__ onw, u16* __restrict__ OH, u16* __restrict__ OL)
{
  int gi = blockIdx.x * 4 + (threadIdx.x >> 6);
  int lane = threadIdx.x & 63;
  size_t idx = (size_t)gi * 64 + lane;
  float x = o[idx];
  float ss = x * x;
#pragma unroll
  for (int d2 = 32; d2 >= 1; d2 >>= 1) ss += __shfl_xor(ss, d2, 64);
  float r = rsqrtf(ss * (1.f / 64.f) + 1e-5f);
  float y = x * r * onw[lane] * gsil[idx];
  u16 h, l;
  split2_(y, h, l);
  OH[idx] = h;
  OL[idx] = l;
}

// ---------------------------------------------------------------------------
// Host launcher
// ---------------------------------------------------------------------------
extern "C" void kernel_launch(void* const* d_in, const int* in_sizes, int n_in,
                              void* d_out, int out_size, void* d_ws, size_t ws_size,
                              hipStream_t stream)
{
  const float* hs  = (const float*)d_in[0];
  const float* Wq  = (const float*)d_in[1];
  const float* bq  = (const float*)d_in[2];
  const float* Wk  = (const float*)d_in[3];
  const float* bk  = (const float*)d_in[4];
  const float* Wv  = (const float*)d_in[5];
  const float* bv  = (const float*)d_in[6];
  const float* Wb  = (const float*)d_in[7];
  const float* bb  = (const float*)d_in[8];
  const float* Wfd = (const float*)d_in[9];
  const float* bfd = (const float*)d_in[10];
  const float* fdb = (const float*)d_in[11];
  const float* Wsd = (const float*)d_in[12];
  const float* bsd = (const float*)d_in[13];
  const float* sdb = (const float*)d_in[14];
  const float* Wfg = (const float*)d_in[15];
  const float* bfg = (const float*)d_in[16];
  const float* Wsg = (const float*)d_in[17];
  const float* bsg = (const float*)d_in[18];
  const float* Wg  = (const float*)d_in[19];
  const float* bg  = (const float*)d_in[20];
  const float* onw = (const float*)d_in[21];
  const float* Wo  = (const float*)d_in[22];
  const float* bo  = (const float*)d_in[23];
  const float* rfx = (const float*)d_in[24];

  float* ws = (float*)d_ws;
  const size_t TWO_M = (size_t)1 << 21;  // 2M floats = B*L*D
  float* q_ws  = ws;
  float* k_ws  = ws + TWO_M;
  float* v_ws  = ws + 2 * TWO_M;
  float* g_ws  = ws + 3 * TWO_M;
  float* o_ws  = ws + 4 * TWO_M;
  float* scl_ws = ws + 5 * TWO_M;            // 262144 floats
  u16*   wt    = (u16*)(ws + 5 * TWO_M + 262144);  // 5 x (1M hi + 1M lo) u16
  u16* hs_hi = (u16*)o_ws;                   // overlays o_ws until scan
  u16* hs_lo = (u16*)(o_ws + TWO_M / 2);
  u16* og_hi = (u16*)v_ws;                   // overlays v_ws after scan
  u16* og_lo = (u16*)(v_ws + TWO_M / 2);

  const size_t WSZ = 1048576;
  u16* WqTh = wt;               u16* WqTl = wt + WSZ;
  u16* WkTh = wt + 2 * WSZ;     u16* WkTl = wt + 3 * WSZ;
  u16* WvTh = wt + 4 * WSZ;     u16* WvTl = wt + 5 * WSZ;
  u16* WgTh = wt + 6 * WSZ;     u16* WgTl = wt + 7 * WSZ;
  u16* WoTh = wt + 8 * WSZ;     u16* WoTl = wt + 9 * WSZ;

  // 0) split hs into bf16 hi/lo
  split_mk<<<2048, 256, 0, stream>>>(hs, hs_hi, hs_lo, (int)(TWO_M / 4));

  // 0b) transpose + split the 5 big weight matrices
  WSplitBatch wb;
  wb.s[0] = { Wq, WqTh, WqTl };
  wb.s[1] = { Wk, WkTh, WkTl };
  wb.s[2] = { Wv, WvTh, WvTl };
  wb.s[3] = { Wg, WgTh, WgTl };
  wb.s[4] = { Wo, WoTh, WoTl };
  splitT<<<dim3(32, 32, 5), 256, 0, stream>>>(wb);

  // 1) big projections via split-bf16 MFMA (reg-double-buffered)
  MBatch gb1;
  gb1.s[0] = { WqTh, WqTl, bq, q_ws, 2 };
  gb1.s[1] = { WkTh, WkTl, bk, k_ws, 2 };
  gb1.s[2] = { WvTh, WvTl, bv, v_ws, 2 };
  gb1.s[3] = { WgTh, WgTl, bg, g_ws, 1 };
  gemm_mfma<<<dim3(16, 16, 4), 256, 0, stream>>>(hs_hi, hs_lo, gb1, 2048, 1024, 1024);

  // 2) per-head scalar projections
  scalar_proj<<<256, 256, 0, stream>>>(hs, Wb, bb, Wfd, bfd, fdb, Wsd, bsd, sdb,
                                       Wfg, bfg, Wsg, bsg, scl_ws);

  // 3) pre-normalize q,k
  prenorm<<<16384, 256, 0, stream>>>(q_ws);

  // 4) sequential dual-state delta-rule scan (unchanged r13)
  scan_kernel<<<32, 512, 0, stream>>>(q_ws, k_ws, v_ws, scl_ws, rfx, o_ws);

  // 5) gated RMSNorm fused with bf16 split -> og_hi/og_lo
  rms_gate_split<<<8192, 256, 0, stream>>>(o_ws, g_ws, onw, og_hi, og_lo);

  // 6) output projection via split-bf16 MFMA -> d_out
  MBatch gb2;
  gb2.s[0] = { WoTh, WoTl, bo, (float*)d_out, 0 };
  gb2.s[1] = gb2.s[0]; gb2.s[2] = gb2.s[0]; gb2.s[3] = gb2.s[0];
  gemm_mfma<<<dim3(16, 16, 1), 256, 0, stream>>>(og_hi, og_lo, gb2, 2048, 1024, 1024);
}